// Round 20
// baseline (794.541 us; speedup 1.0000x reference)
//
#include <hip/hip_runtime.h>

#define NN 100000
#define NE 3200000
#define NB 98   // ceil(NN/1024)

typedef unsigned int u32;
typedef unsigned short u16;
typedef _Float16 f16x2 __attribute__((ext_vector_type(2)));
typedef _Float16 f16x8 __attribute__((ext_vector_type(8)));
typedef float fltx4 __attribute__((ext_vector_type(4)));
typedef __fp16 fp16v2 __attribute__((ext_vector_type(2)));

__device__ __forceinline__ int clampi(int s){
  s = s < 0 ? 0 : s;
  return s >= NN ? NN-1 : s;
}

__device__ __forceinline__ f16x2 pk2(float x, float y){
  fp16v2 r = __builtin_amdgcn_cvt_pkrtz(x, y);
  return __builtin_bit_cast(f16x2, r);
}
__device__ __forceinline__ u32 pk2u(float x, float y){
  return __builtin_bit_cast(u32, pk2(x, y));
}
__device__ __forceinline__ float dot2(f16x2 a, f16x2 b, float c){
  return __builtin_amdgcn_fdot2(a, b, c, false);
}
__device__ __forceinline__ float f16lo(u32 w){
  __fp16 h = __builtin_bit_cast(__fp16, (u16)(w & 0xffffu));
  return (float)h;
}
__device__ __forceinline__ float f16hi(u32 w){
  __fp16 h = __builtin_bit_cast(__fp16, (u16)(w >> 16));
  return (float)h;
}
__device__ __forceinline__ float f16u(u16 w){
  __fp16 h = __builtin_bit_cast(__fp16, w);
  return (float)h;
}

// ---------------- khist: cnt[d]++ ------------------------------------------
__global__ __launch_bounds__(256,8) void khist(const int* __restrict__ ei, int* __restrict__ cnt){
  int i = blockIdx.x*256 + threadIdx.x;
  if (i >= NE) return;
  atomicAdd(&cnt[clampi(ei[NE+i])], 1);
}

// ---------------- kscanA: per-block sums of cnt -----------------------------
__global__ __launch_bounds__(1024) void kscanA(const int* __restrict__ cnt, int* __restrict__ bsum){
  __shared__ int wsum[16];
  int tid = threadIdx.x;
  int i = blockIdx.x*1024 + tid;
  int x = (i < NN) ? cnt[i] : 0;
  #pragma unroll
  for (int ofs = 1; ofs < 64; ofs <<= 1) x += __shfl_xor(x, ofs, 64);
  if ((tid & 63) == 0) wsum[tid >> 6] = x;
  __syncthreads();
  if (tid == 0){
    int t = 0;
    #pragma unroll
    for (int k = 0; k < 16; k++) t += wsum[k];
    bsum[blockIdx.x] = t;
  }
}

// ---------------- kscanB: scan the 98 block sums ----------------------------
__global__ void kscanB(const int* __restrict__ bsum, int* __restrict__ boff, int* __restrict__ offN){
  if (threadIdx.x == 0){
    int c = 0;
    for (int b = 0; b < NB; b++){ boff[b] = c; c += bsum[b]; }
    offN[0] = c;
  }
}

// ---------------- kscanC: block-local scan + offset; cnt = 0 ----------------
__global__ __launch_bounds__(1024) void kscanC(int* __restrict__ cnt, const int* __restrict__ boff,
                                               int* __restrict__ off){
  __shared__ int wsum[16];
  int tid = threadIdx.x;
  int i = blockIdx.x*1024 + tid;
  int v = (i < NN) ? cnt[i] : 0;
  int x = v;
  #pragma unroll
  for (int ofs = 1; ofs < 64; ofs <<= 1){
    int t = __shfl_up(x, ofs, 64);
    if ((tid & 63) >= ofs) x += t;
  }
  if ((tid & 63) == 63) wsum[tid >> 6] = x;
  __syncthreads();
  if (tid < 16){
    int y = wsum[tid];
    #pragma unroll
    for (int ofs = 1; ofs < 16; ofs <<= 1){
      int t = __shfl_up(y, ofs, 64);
      if (tid >= ofs) y += t;
    }
    wsum[tid] = y;
  }
  __syncthreads();
  int wb = (tid >= 64) ? wsum[(tid >> 6) - 1] : 0;
  if (i < NN){ off[i] = boff[blockIdx.x] + wb + x - v; cnt[i] = 0; }
}

// ---------------- k1: hs1 = (Wx x).a_src ; hd1 = (Wx x).a_dst ---------------
__global__ __launch_bounds__(256,4) void k1(const float* __restrict__ x,
    const float* __restrict__ Wx, const float* __restrict__ asrc, const float* __restrict__ adst,
    float* __restrict__ hs1, float* __restrict__ hd1)
{
  __shared__ float wL[64], aS[16], aD[16];
  int tid = threadIdx.x;
  if (tid < 64) wL[tid] = Wx[tid];
  if (tid < 16){ aS[tid] = asrc[tid]; aD[tid] = adst[tid]; }
  __syncthreads();
  int n = blockIdx.x*256 + tid;
  if (n >= NN) return;
  float4 xr = ((const float4*)x)[n];
  float hs=0.f, hd=0.f;
  #pragma unroll
  for (int j=0;j<16;j++){
    float h = xr.x*wL[j*4+0] + xr.y*wL[j*4+1] + xr.z*wL[j*4+2] + xr.w*wL[j*4+3];
    hs += h*aS[j]; hd += h*aD[j];
  }
  hs1[n]=hs; hd1[n]=hd;
}

// ---------------- k2a: alpha1 -> CSR scatter (known-good) -------------------
__global__ __launch_bounds__(256,8) void k2a(const int* __restrict__ ei,
    const float* __restrict__ ea, const float* __restrict__ We, const float* __restrict__ aedge,
    const float* __restrict__ hs1, const float* __restrict__ hd1,
    const int* __restrict__ off, int* __restrict__ cnt, float2* __restrict__ edata)
{
  __shared__ float w6[6];
  int tid = threadIdx.x;
  if (tid < 6){
    float acc = 0.f;
    for (int j=0;j<16;j++) acc += aedge[j] * We[j*6+tid];
    w6[tid] = acc;
  }
  __syncthreads();
  int i = blockIdx.x*256 + tid;
  if (i >= NE) return;
  int s = clampi(ei[i]);
  int d = clampi(ei[NE + i]);
  const float2* eap = (const float2*)ea + (size_t)i*3;
  float2 u0 = eap[0], u1 = eap[1], u2 = eap[2];
  float al = hs1[s] + hd1[d]
    + u0.x*w6[0] + u0.y*w6[1] + u1.x*w6[2]
    + u1.y*w6[3] + u2.x*w6[4] + u2.y*w6[5];
  al = al > 0.f ? al : 0.2f*al;
  float ex = __expf(al);
  int pos = off[d] + atomicAdd(&cnt[d], 1);
  edata[pos] = make_float2(ex, __int_as_float(s));
}

// ---------------- k34: conv1 CSR reduce + node transform --------------------
__global__ __launch_bounds__(256,8) void k34(const float2* __restrict__ edata,
    const int* __restrict__ off, const float* __restrict__ x,
    const float* __restrict__ c1b, const float* __restrict__ Wx1, const float* __restrict__ Wx2,
    const float* __restrict__ a2s, const float* __restrict__ a2d,
    const float* __restrict__ w1p,
    u32* __restrict__ hpk, float* __restrict__ hs2, float* __restrict__ hd2,
    u32* __restrict__ uh, u32* __restrict__ vh, int* __restrict__ cnt)
{
  __shared__ float w0L[64], bL[16], wL[256], aS[16], aD[16];
  __shared__ float w1sL[32*16], w1dL[32*16];
  int tid = threadIdx.x;
  wL[tid] = Wx2[tid];
  if (tid < 64) w0L[tid] = Wx1[tid];
  if (tid < 16){ bL[tid]=c1b[tid]; aS[tid]=a2s[tid]; aD[tid]=a2d[tid]; }
  for (int idx=tid; idx<512; idx+=256){
    int j=idx>>4, k=idx&15;
    w1sL[idx] = w1p[j*38+k];
    w1dL[idx] = w1p[j*38+22+k];
  }
  __syncthreads();
  int t = blockIdx.x*256 + tid;
  int n = t >> 4;
  int j = t & 15;
  if (n >= NN) return;
  int f = j & 3, ks = j >> 2;
  int beg = off[n], end = off[n+1];
  float aj = 0.f, sl = 0.f;
  for (int k = beg + ks; k < end; k += 4){
    float2 p = edata[k];
    int src = __float_as_int(p.y);
    aj += p.x * x[(size_t)src*4 + f];
    sl += p.x;
  }
  aj += __shfl_xor(aj, 4, 64); aj += __shfl_xor(aj, 8, 64);
  sl += __shfl_xor(sl, 4, 64); sl += __shfl_xor(sl, 8, 64);
  float inv = 1.f/(sl + 1e-16f);
  float m0 = __shfl(aj, 0, 16)*inv;
  float m1 = __shfl(aj, 1, 16)*inv;
  float m2 = __shfl(aj, 2, 16)*inv;
  float m3 = __shfl(aj, 3, 16)*inv;
  float xvj = m0*w0L[j*4+0] + m1*w0L[j*4+1] + m2*w0L[j*4+2] + m3*w0L[j*4+3] + bL[j];
  float hv = 0.f, u0=0.f, u1=0.f, v0=0.f, v1=0.f;
  #pragma unroll
  for (int k=0;k<16;k++){
    float vk = __shfl(xvj, k, 16);
    hv += vk * wL[j*16+k];
    u0 += vk * w1sL[(2*j)*16+k];
    u1 += vk * w1sL[(2*j+1)*16+k];
    v0 += vk * w1dL[(2*j)*16+k];
    v1 += vk * w1dL[(2*j+1)*16+k];
  }
  ((u16*)hpk)[(size_t)n*16 + j] = (u16)(pk2u(hv, 0.f) & 0xffffu);
  uh[(size_t)n*16 + j] = pk2u(u0, u1);
  vh[(size_t)n*16 + j] = pk2u(v0, v1);
  float hsp = hv*aS[j], hdp = hv*aD[j];
  #pragma unroll
  for (int ofs=1; ofs<16; ofs<<=1){
    hsp += __shfl_xor(hsp, ofs, 64);
    hdp += __shfl_xor(hdp, ofs, 64);
  }
  if (j == 0){ hs2[n]=hsp; hd2[n]=hdp; cnt[n]=0; }
}

// ---------------- k5m: edge MLP with MFMA L2/L3 + folded head + scatter -----
// r18 sync structure (__syncthreads -- r19 showed wsync/sched_barrier(0)
// costs +70us by pinning the scheduler) + r19's padded LDS strides
// (conflicts 2.24e7 -> 2.4e6) + global per-lane B-frag loads (L2-hot).
#define A13S 20
#define A2S  36
__global__ __launch_bounds__(256,4) void k5m(
    const int* __restrict__ ei, const float* __restrict__ ea,
    const u32* __restrict__ uh, const u32* __restrict__ vh,
    const float* __restrict__ hs2, const float* __restrict__ hd2,
    const float* w1p, const float* b1p, const float* w2p, const float* b2p,
    const float* w3p, const float* b3p, const float* w4p, const float* b4p,
    const float* We2, const float* a2e,
    const float* ew1p, const float* eb1p, const float* ew2p, const float* eb2p,
    const int* __restrict__ off, int* __restrict__ cnt, float2* __restrict__ edata,
    float* __restrict__ eout)
{
  __shared__ __align__(16) u32 a13L[4][64*A13S];   // per-wave 5120B: a1, later a3
  __shared__ __align__(16) u32 a2L[4][16*A2S];     // per-wave 2304B: a2 row-tile
  __shared__ __align__(16) f16x2 w1eh[32*4];  __shared__ float b1L[32];
  __shared__ float b2L[64], b3L[32];
  __shared__ __align__(16) f16x2 M1h[16*16];  __shared__ float c1L[16];
  __shared__ __align__(16) f16x2 ew2h[4*8];   __shared__ float eb2L[4];
  __shared__ __align__(16) f16x2 w16w4h[16];
  __shared__ float w16L[16];  __shared__ float w16b4L;

  int tid = threadIdx.x;
  // ---- init phase A (cross-wave shared weights) ----
  if (tid < 128){
    int j=tid>>2, kk=tid&3;
    int k0=2*kk, k1=2*kk+1;
    float v0 = (k0<6) ? w1p[j*38+16+k0] : 0.f;
    float v1 = (k1<6) ? w1p[j*38+16+k1] : 0.f;
    w1eh[tid] = pk2(v0, v1);
  }
  if (tid < 64) b2L[tid] = b2p[tid];
  if (tid < 32){ b1L[tid] = b1p[tid]; b3L[tid] = b3p[tid]; }
  {
    int o = tid>>4, p = tid&15;
    float m0=0.f, m1=0.f;
    #pragma unroll
    for (int q=0;q<16;q++){
      float w = ew1p[o*16+q];
      m0 += w * w4p[q*32 + 2*p];
      m1 += w * w4p[q*32 + 2*p + 1];
    }
    M1h[o*16+p] = pk2(m0, m1);
  }
  if (tid < 16){
    float acc = eb1p[tid];
    for (int q=0;q<16;q++) acc += ew1p[tid*16+q]*b4p[q];
    c1L[tid] = acc;
    float w=0.f;
    for (int j=0;j<16;j++) w += a2e[j] * We2[j*16+tid];
    w16L[tid] = w;
  }
  if (tid < 32){
    int j=tid>>3, kk=tid&7;
    ew2h[tid] = pk2(ew2p[j*16+2*kk], ew2p[j*16+2*kk+1]);
  }
  if (tid < 4) eb2L[tid] = eb2p[tid];
  __syncthreads();
  // ---- init phase B (needs w16L) ----
  if (tid < 16){
    float s0=0.f, s1=0.f;
    for (int q=0;q<16;q++){
      s0 += w16L[q]*w4p[q*32 + 2*tid];
      s1 += w16L[q]*w4p[q*32 + 2*tid + 1];
    }
    w16w4h[tid] = pk2(s0, s1);
  }
  if (tid == 0){
    float acc=0.f;
    for (int q=0;q<16;q++) acc += w16L[q]*b4p[q];
    w16b4L = acc;
  }
  __syncthreads();

  int wid = tid>>6, lane = tid&63;
  int cl = lane & 15, g = lane >> 4;
  u32* a13 = a13L[wid];
  u32* a2u = a2L[wid];
  int i = blockIdx.x*256 + tid;   // always < NE (grid exact)
  int s = clampi(ei[i]);
  int d = clampi(ei[NE + i]);

  // ---- B fragments loaded per-lane from global (w2/w3 are L2-hot) ----
  f16x8 fb2[4], fb3[4];
  #pragma unroll
  for (int c=0;c<4;c++){
    const float* src = w2p + (c*16 + cl)*32 + g*8;
    uint4 q;
    q.x = pk2u(src[0], src[1]); q.y = pk2u(src[2], src[3]);
    q.z = pk2u(src[4], src[5]); q.w = pk2u(src[6], src[7]);
    fb2[c] = __builtin_bit_cast(f16x8, q);
  }
  #pragma unroll
  for (int kt=0;kt<2;kt++)
  #pragma unroll
  for (int c=0;c<2;c++){
    const float* src = w3p + (c*16 + cl)*64 + kt*32 + g*8;
    uint4 q;
    q.x = pk2u(src[0], src[1]); q.y = pk2u(src[2], src[3]);
    q.z = pk2u(src[4], src[5]); q.w = pk2u(src[6], src[7]);
    fb3[kt*2+c] = __builtin_bit_cast(f16x8, q);
  }

  // ---- layer 1 (per-lane, f16 dot2) ----
  u32 a1h[16];
  {
    const float2* eap = (const float2*)ea + (size_t)i*3;
    float2 e0=eap[0], e1=eap[1], e2=eap[2];
    f16x2 eh[4];
    eh[0]=pk2(e0.x,e0.y); eh[1]=pk2(e1.x,e1.y); eh[2]=pk2(e2.x,e2.y); eh[3]=pk2(0.f,0.f);
    const uint4* up = (const uint4*)(uh + (size_t)s*16);
    const uint4* vp = (const uint4*)(vh + (size_t)d*16);
    uint4 U[4], V[4];
    #pragma unroll
    for (int q=0;q<4;q++){ U[q]=up[q]; V[q]=vp[q]; }
    u32 uw[16], vw[16];
    #pragma unroll
    for (int q=0;q<4;q++){
      uw[4*q]=U[q].x; uw[4*q+1]=U[q].y; uw[4*q+2]=U[q].z; uw[4*q+3]=U[q].w;
      vw[4*q]=V[q].x; vw[4*q+1]=V[q].y; vw[4*q+2]=V[q].z; vw[4*q+3]=V[q].w;
    }
    #pragma unroll
    for (int j=0;j<16;j++){
      float t0 = b1L[2*j]   + f16lo(uw[j]) + f16lo(vw[j]);
      float t1 = b1L[2*j+1] + f16hi(uw[j]) + f16hi(vw[j]);
      #pragma unroll
      for (int kk=0;kk<4;kk++){
        t0 = dot2(eh[kk], w1eh[(2*j)*4+kk],   t0);
        t1 = dot2(eh[kk], w1eh[(2*j+1)*4+kk], t1);
      }
      a1h[j] = pk2u(fmaxf(t0,0.f), fmaxf(t1,0.f));
    }
  }
  // stage a1: row = lane, padded stride
  {
    uint4* dst = (uint4*)(a13 + lane*A13S);
    dst[0] = make_uint4(a1h[0],a1h[1],a1h[2],a1h[3]);
    dst[1] = make_uint4(a1h[4],a1h[5],a1h[6],a1h[7]);
    dst[2] = make_uint4(a1h[8],a1h[9],a1h[10],a1h[11]);
    dst[3] = make_uint4(a1h[12],a1h[13],a1h[14],a1h[15]);
  }
  __syncthreads();

  // ---- L2 + L3 per row-tile ----
  #pragma unroll
  for (int r=0;r<4;r++){
    __syncthreads();                 // a2 WAR from previous r
    uint4 av = *(const uint4*)(a13 + (r*16 + cl)*A13S + g*4);
    f16x8 af = __builtin_bit_cast(f16x8, av);
    _Float16* a2h_ = (_Float16*)a2u;
    #pragma unroll
    for (int c=0;c<4;c++){
      float b = b2L[c*16 + cl];
      fltx4 acc = {b,b,b,b};
      acc = __builtin_amdgcn_mfma_f32_16x16x32_f16(af, fb2[c], acc, 0, 0, 0);
      int col = c*16 + cl;
      int rowb = g*4;
      a2h_[(rowb+0)*(2*A2S) + col] = (_Float16)fmaxf(acc[0], 0.f);
      a2h_[(rowb+1)*(2*A2S) + col] = (_Float16)fmaxf(acc[1], 0.f);
      a2h_[(rowb+2)*(2*A2S) + col] = (_Float16)fmaxf(acc[2], 0.f);
      a2h_[(rowb+3)*(2*A2S) + col] = (_Float16)fmaxf(acc[3], 0.f);
    }
    __syncthreads();                 // a2 ready
    uint4 a20 = *(const uint4*)(a2u + cl*A2S + g*4);
    uint4 a21 = *(const uint4*)(a2u + cl*A2S + 16 + g*4);
    f16x8 af0 = __builtin_bit_cast(f16x8, a20);
    f16x8 af1 = __builtin_bit_cast(f16x8, a21);
    _Float16* a3w = (_Float16*)a13;
    #pragma unroll
    for (int c=0;c<2;c++){
      float b = b3L[c*16 + cl];
      fltx4 acc = {b,b,b,b};
      acc = __builtin_amdgcn_mfma_f32_16x16x32_f16(af0, fb3[0*2+c], acc, 0, 0, 0);
      acc = __builtin_amdgcn_mfma_f32_16x16x32_f16(af1, fb3[1*2+c], acc, 0, 0, 0);
      int col = c*16 + cl;
      int row = r*16 + g*4;
      a3w[(row+0)*(2*A13S) + col] = (_Float16)fmaxf(acc[0], 0.f);
      a3w[(row+1)*(2*A13S) + col] = (_Float16)fmaxf(acc[1], 0.f);
      a3w[(row+2)*(2*A13S) + col] = (_Float16)fmaxf(acc[2], 0.f);
      a3w[(row+3)*(2*A13S) + col] = (_Float16)fmaxf(acc[3], 0.f);
    }
  }
  __syncthreads();                   // a3 complete
  // readback a3 of own edge
  u32 a3h[16];
  {
    const uint4* srcp = (const uint4*)(a13 + lane*A13S);
    uint4 q0=srcp[0], q1=srcp[1], q2=srcp[2], q3=srcp[3];
    a3h[0]=q0.x; a3h[1]=q0.y; a3h[2]=q0.z; a3h[3]=q0.w;
    a3h[4]=q1.x; a3h[5]=q1.y; a3h[6]=q1.z; a3h[7]=q1.w;
    a3h[8]=q2.x; a3h[9]=q2.y; a3h[10]=q2.z; a3h[11]=q2.w;
    a3h[12]=q3.x; a3h[13]=q3.y; a3h[14]=q3.z; a3h[15]=q3.w;
  }
  // ---- folded L4 + head1: t = relu(M1.a3 + c1) ----
  f16x2 th[8];
  #pragma unroll
  for (int o=0;o<8;o++){
    float t0 = c1L[2*o], t1 = c1L[2*o+1];
    #pragma unroll
    for (int kp=0;kp<16;kp++){
      f16x2 a = __builtin_bit_cast(f16x2, a3h[kp]);
      t0 = dot2(a, M1h[(2*o)*16+kp],   t0);
      t1 = dot2(a, M1h[(2*o+1)*16+kp], t1);
    }
    th[o] = pk2(fmaxf(t0,0.f), fmaxf(t1,0.f));
  }
  // ---- head2 + log_softmax(4) ----
  float y0 = eb2L[0], y1 = eb2L[1], y2 = eb2L[2], y3 = eb2L[3];
  #pragma unroll
  for (int kk=0;kk<8;kk++){
    y0 = dot2(th[kk], ew2h[0*8+kk], y0);
    y1 = dot2(th[kk], ew2h[1*8+kk], y1);
    y2 = dot2(th[kk], ew2h[2*8+kk], y2);
    y3 = dot2(th[kk], ew2h[3*8+kk], y3);
  }
  y0 = fmaxf(y0,0.f); y1 = fmaxf(y1,0.f); y2 = fmaxf(y2,0.f); y3 = fmaxf(y3,0.f);
  float m = fmaxf(fmaxf(y0,y1), fmaxf(y2,y3));
  float l = m + __logf(__expf(y0-m)+__expf(y1-m)+__expf(y2-m)+__expf(y3-m));
  float4 eo; eo.x = y0-l; eo.y = y1-l; eo.z = y2-l; eo.w = y3-l;
  ((float4*)eout)[i] = eo;

  // ---- conv2 alpha via folded w16w4 ----
  float al = hs2[s] + hd2[d] + w16b4L;
  #pragma unroll
  for (int kp=0;kp<16;kp++){
    f16x2 a = __builtin_bit_cast(f16x2, a3h[kp]);
    al = dot2(a, w16w4h[kp], al);
  }
  al = al > 0.f ? al : 0.2f*al;
  float ex = __expf(al);
  int pos = off[d] + atomicAdd(&cnt[d], 1);
  edata[pos] = make_float2(ex, __int_as_float(s));
}

// ---------------- kagg2: conv2 CSR reduce + fused node head ----------------
__global__ __launch_bounds__(256,8) void kagg2(const float2* __restrict__ edata,
    const int* __restrict__ off, const u16* __restrict__ hpk,
    const float* __restrict__ c2b,
    const float* __restrict__ w1p, const float* __restrict__ b1p,
    const float* __restrict__ w2p, const float* __restrict__ b2p,
    float* __restrict__ nout, int* __restrict__ cnt)
{
  __shared__ float w1L[256], cb[16], b1L[16], w2L[32], b2L[2];
  int tid = threadIdx.x;
  w1L[tid] = w1p[tid];
  if (tid < 16){ cb[tid] = c2b[tid]; b1L[tid] = b1p[tid]; }
  if (tid < 32) w2L[tid] = w2p[tid];
  if (tid < 2)  b2L[tid] = b2p[tid];
  __syncthreads();
  int t = blockIdx.x*256 + tid;
  int n = t >> 6;
  int l = t & 63;
  if (n >= NN) return;
  int j = l & 15, ks = l >> 4;
  int beg = off[n], end = off[n+1];
  float aj = 0.f, sl = 0.f;
  for (int k = beg + ks; k < end; k += 4){
    float2 p = edata[k];
    int src = __float_as_int(p.y);
    aj += p.x * f16u(hpk[(size_t)src*16 + j]);
    sl += p.x;
  }
  aj += __shfl_xor(aj, 16, 64); aj += __shfl_xor(aj, 32, 64);
  sl += __shfl_xor(sl, 16, 64); sl += __shfl_xor(sl, 32, 64);
  float inv = 1.f/(sl + 1e-16f);
  float vj = aj*inv + cb[j];
  float tj = b1L[j];
  #pragma unroll
  for (int k=0;k<16;k++){
    float vk = __shfl(vj, k, 16);
    tj += vk * w1L[j*16 + k];
  }
  tj = fmaxf(tj, 0.f);
  float p0 = tj * w2L[j];
  float p1 = tj * w2L[16 + j];
  #pragma unroll
  for (int ofs=1; ofs<16; ofs<<=1){
    p0 += __shfl_xor(p0, ofs, 64);
    p1 += __shfl_xor(p1, ofs, 64);
  }
  if (l == 0){
    float y0 = fmaxf(p0 + b2L[0], 0.f);
    float y1 = fmaxf(p1 + b2L[1], 0.f);
    float m = fmaxf(y0, y1);
    float lg = m + __logf(__expf(y0-m) + __expf(y1-m));
    float2 no; no.x = y0-lg; no.y = y1-lg;
    ((float2*)nout)[n] = no;
    cnt[n] = 0;
  }
}

extern "C" void kernel_launch(void* const* d_in, const int* in_sizes, int n_in,
                              void* d_out, int out_size, void* d_ws, size_t ws_size,
                              hipStream_t stream)
{
  const float* x  = (const float*)d_in[0];
  const int* ei   = (const int*)d_in[1];
  const float* ea = (const float*)d_in[2];
  const float* c1Wx = (const float*)d_in[3];
  const float* c1We = (const float*)d_in[4];
  const float* c1as = (const float*)d_in[5];
  const float* c1ad = (const float*)d_in[6];
  const float* c1ae = (const float*)d_in[7];
  const float* c1b  = (const float*)d_in[8];
  const float* e1w1 = (const float*)d_in[9];
  const float* e1b1 = (const float*)d_in[10];
  const float* e1w2 = (const float*)d_in[11];
  const float* e1b2 = (const float*)d_in[12];
  const float* e1w3 = (const float*)d_in[13];
  const float* e1b3 = (const float*)d_in[14];
  const float* e1w4 = (const float*)d_in[15];
  const float* e1b4 = (const float*)d_in[16];
  const float* c2Wx = (const float*)d_in[17];
  const float* c2We = (const float*)d_in[18];
  const float* c2as = (const float*)d_in[19];
  const float* c2ad = (const float*)d_in[20];
  const float* c2ae = (const float*)d_in[21];
  const float* c2b  = (const float*)d_in[22];
  const float* nlw1 = (const float*)d_in[23];
  const float* nlb1 = (const float*)d_in[24];
  const float* nlw2 = (const float*)d_in[25];
  const float* nlb2 = (const float*)d_in[26];
  const float* elw1 = (const float*)d_in[27];
  const float* elb1 = (const float*)d_in[28];
  const float* elw2 = (const float*)d_in[29];
  const float* elb2 = (const float*)d_in[30];

  float* ws = (float*)d_ws;
  const size_t N = NN;
  int* off   = (int*)ws;                     // N+8
  int* cnt   = (int*)ws + (N + 8);           // N
  int* bsum  = (int*)ws + (2*N + 8);         // 128
  int* boff  = (int*)ws + (2*N + 136);       // 128
  u32* hpk   = (u32*)(ws + 2*N + 264);       // 8N u32 (f16x2-packed h2)
  float* hs  = ws + 10*N + 264;              // N
  float* hd  = hs + N;                       // N
  u32* uh    = (u32*)(hd + N);               // 16N u32
  u32* vh    = uh + 16*N;                    // 16N u32
  float2* edata = (float2*)(vh + 16*N);      // NE float2

  float* nout = (float*)d_out;               // [100000, 2]
  float* eout = (float*)d_out + 200000;      // [3200000, 4]

  const int GE = (NE + 255)/256;
  const int GN = (NN + 255)/256;

  (void)hipMemsetAsync(cnt, 0, N*sizeof(int), stream);
  khist<<<GE, 256, 0, stream>>>(ei, cnt);
  kscanA<<<NB, 1024, 0, stream>>>(cnt, bsum);
  kscanB<<<1, 64, 0, stream>>>(bsum, boff, off + NN);
  kscanC<<<NB, 1024, 0, stream>>>(cnt, boff, off);
  k1<<<GN, 256, 0, stream>>>(x, c1Wx, c1as, c1ad, hs, hd);
  k2a<<<GE, 256, 0, stream>>>(ei, ea, c1We, c1ae, hs, hd, off, cnt, edata);
  k34<<<(NN*16 + 255)/256, 256, 0, stream>>>(edata, off, x,
      c1b, c1Wx, c2Wx, c2as, c2ad, e1w1, hpk, hs, hd, uh, vh, cnt);
  k5m<<<GE, 256, 0, stream>>>(ei, ea, uh, vh, hs, hd,
      e1w1, e1b1, e1w2, e1b2, e1w3, e1b3, e1w4, e1b4,
      c2We, c2ae, elw1, elb1, elw2, elb2,
      off, cnt, edata, eout);
  kagg2<<<(NN*64 + 255)/256, 256, 0, stream>>>(edata, off, (const u16*)hpk,
      c2b, nlw1, nlb1, nlw2, nlb2, nout, cnt);
}

// Round 21
// 742.963 us; speedup vs baseline: 1.0694x; 1.0694x over previous
//
#include <hip/hip_runtime.h>

#define NN 100000
#define NE 3200000
#define NB 98   // ceil(NN/1024)

typedef unsigned int u32;
typedef unsigned short u16;
typedef _Float16 f16x2 __attribute__((ext_vector_type(2)));
typedef _Float16 f16x8 __attribute__((ext_vector_type(8)));
typedef float fltx4 __attribute__((ext_vector_type(4)));
typedef __fp16 fp16v2 __attribute__((ext_vector_type(2)));

__device__ __forceinline__ int clampi(int s){
  s = s < 0 ? 0 : s;
  return s >= NN ? NN-1 : s;
}

__device__ __forceinline__ f16x2 pk2(float x, float y){
  fp16v2 r = __builtin_amdgcn_cvt_pkrtz(x, y);
  return __builtin_bit_cast(f16x2, r);
}
__device__ __forceinline__ u32 pk2u(float x, float y){
  return __builtin_bit_cast(u32, pk2(x, y));
}
__device__ __forceinline__ float dot2(f16x2 a, f16x2 b, float c){
  return __builtin_amdgcn_fdot2(a, b, c, false);
}
__device__ __forceinline__ float f16lo(u32 w){
  __fp16 h = __builtin_bit_cast(__fp16, (u16)(w & 0xffffu));
  return (float)h;
}
__device__ __forceinline__ float f16hi(u32 w){
  __fp16 h = __builtin_bit_cast(__fp16, (u16)(w >> 16));
  return (float)h;
}
__device__ __forceinline__ float f16u(u16 w){
  __fp16 h = __builtin_bit_cast(__fp16, w);
  return (float)h;
}

// ---------------- khist: cnt[d]++ ------------------------------------------
__global__ __launch_bounds__(256,8) void khist(const int* __restrict__ ei, int* __restrict__ cnt){
  int i = blockIdx.x*256 + threadIdx.x;
  if (i >= NE) return;
  atomicAdd(&cnt[clampi(ei[NE+i])], 1);
}

// ---------------- kscanA: per-block sums of cnt -----------------------------
__global__ __launch_bounds__(1024) void kscanA(const int* __restrict__ cnt, int* __restrict__ bsum){
  __shared__ int wsum[16];
  int tid = threadIdx.x;
  int i = blockIdx.x*1024 + tid;
  int x = (i < NN) ? cnt[i] : 0;
  #pragma unroll
  for (int ofs = 1; ofs < 64; ofs <<= 1) x += __shfl_xor(x, ofs, 64);
  if ((tid & 63) == 0) wsum[tid >> 6] = x;
  __syncthreads();
  if (tid == 0){
    int t = 0;
    #pragma unroll
    for (int k = 0; k < 16; k++) t += wsum[k];
    bsum[blockIdx.x] = t;
  }
}

// ---------------- kscanB: scan the 98 block sums ----------------------------
__global__ void kscanB(const int* __restrict__ bsum, int* __restrict__ boff, int* __restrict__ offN){
  if (threadIdx.x == 0){
    int c = 0;
    for (int b = 0; b < NB; b++){ boff[b] = c; c += bsum[b]; }
    offN[0] = c;
  }
}

// ---------------- kscanC: block-local scan + offset; cnt = 0 ----------------
__global__ __launch_bounds__(1024) void kscanC(int* __restrict__ cnt, const int* __restrict__ boff,
                                               int* __restrict__ off){
  __shared__ int wsum[16];
  int tid = threadIdx.x;
  int i = blockIdx.x*1024 + tid;
  int v = (i < NN) ? cnt[i] : 0;
  int x = v;
  #pragma unroll
  for (int ofs = 1; ofs < 64; ofs <<= 1){
    int t = __shfl_up(x, ofs, 64);
    if ((tid & 63) >= ofs) x += t;
  }
  if ((tid & 63) == 63) wsum[tid >> 6] = x;
  __syncthreads();
  if (tid < 16){
    int y = wsum[tid];
    #pragma unroll
    for (int ofs = 1; ofs < 16; ofs <<= 1){
      int t = __shfl_up(y, ofs, 64);
      if (tid >= ofs) y += t;
    }
    wsum[tid] = y;
  }
  __syncthreads();
  int wb = (tid >= 64) ? wsum[(tid >> 6) - 1] : 0;
  if (i < NN){ off[i] = boff[blockIdx.x] + wb + x - v; cnt[i] = 0; }
}

// ---------------- k1: hs1 = (Wx x).a_src ; hd1 = (Wx x).a_dst ---------------
__global__ __launch_bounds__(256,4) void k1(const float* __restrict__ x,
    const float* __restrict__ Wx, const float* __restrict__ asrc, const float* __restrict__ adst,
    float* __restrict__ hs1, float* __restrict__ hd1)
{
  __shared__ float wL[64], aS[16], aD[16];
  int tid = threadIdx.x;
  if (tid < 64) wL[tid] = Wx[tid];
  if (tid < 16){ aS[tid] = asrc[tid]; aD[tid] = adst[tid]; }
  __syncthreads();
  int n = blockIdx.x*256 + tid;
  if (n >= NN) return;
  float4 xr = ((const float4*)x)[n];
  float hs=0.f, hd=0.f;
  #pragma unroll
  for (int j=0;j<16;j++){
    float h = xr.x*wL[j*4+0] + xr.y*wL[j*4+1] + xr.z*wL[j*4+2] + xr.w*wL[j*4+3];
    hs += h*aS[j]; hd += h*aD[j];
  }
  hs1[n]=hs; hd1[n]=hd;
}

// ---------------- k2a: alpha1 -> CSR scatter (known-good) -------------------
__global__ __launch_bounds__(256,8) void k2a(const int* __restrict__ ei,
    const float* __restrict__ ea, const float* __restrict__ We, const float* __restrict__ aedge,
    const float* __restrict__ hs1, const float* __restrict__ hd1,
    const int* __restrict__ off, int* __restrict__ cnt, float2* __restrict__ edata)
{
  __shared__ float w6[6];
  int tid = threadIdx.x;
  if (tid < 6){
    float acc = 0.f;
    for (int j=0;j<16;j++) acc += aedge[j] * We[j*6+tid];
    w6[tid] = acc;
  }
  __syncthreads();
  int i = blockIdx.x*256 + tid;
  if (i >= NE) return;
  int s = clampi(ei[i]);
  int d = clampi(ei[NE + i]);
  const float2* eap = (const float2*)ea + (size_t)i*3;
  float2 u0 = eap[0], u1 = eap[1], u2 = eap[2];
  float al = hs1[s] + hd1[d]
    + u0.x*w6[0] + u0.y*w6[1] + u1.x*w6[2]
    + u1.y*w6[3] + u2.x*w6[4] + u2.y*w6[5];
  al = al > 0.f ? al : 0.2f*al;
  float ex = __expf(al);
  int pos = off[d] + atomicAdd(&cnt[d], 1);
  edata[pos] = make_float2(ex, __int_as_float(s));
}

// ---------------- k34: conv1 CSR reduce + node transform --------------------
__global__ __launch_bounds__(256,8) void k34(const float2* __restrict__ edata,
    const int* __restrict__ off, const float* __restrict__ x,
    const float* __restrict__ c1b, const float* __restrict__ Wx1, const float* __restrict__ Wx2,
    const float* __restrict__ a2s, const float* __restrict__ a2d,
    const float* __restrict__ w1p,
    u32* __restrict__ hpk, float* __restrict__ hs2, float* __restrict__ hd2,
    u32* __restrict__ uh, u32* __restrict__ vh, int* __restrict__ cnt)
{
  __shared__ float w0L[64], bL[16], wL[256], aS[16], aD[16];
  __shared__ float w1sL[32*16], w1dL[32*16];
  int tid = threadIdx.x;
  wL[tid] = Wx2[tid];
  if (tid < 64) w0L[tid] = Wx1[tid];
  if (tid < 16){ bL[tid]=c1b[tid]; aS[tid]=a2s[tid]; aD[tid]=a2d[tid]; }
  for (int idx=tid; idx<512; idx+=256){
    int j=idx>>4, k=idx&15;
    w1sL[idx] = w1p[j*38+k];
    w1dL[idx] = w1p[j*38+22+k];
  }
  __syncthreads();
  int t = blockIdx.x*256 + tid;
  int n = t >> 4;
  int j = t & 15;
  if (n >= NN) return;
  int f = j & 3, ks = j >> 2;
  int beg = off[n], end = off[n+1];
  float aj = 0.f, sl = 0.f;
  for (int k = beg + ks; k < end; k += 4){
    float2 p = edata[k];
    int src = __float_as_int(p.y);
    aj += p.x * x[(size_t)src*4 + f];
    sl += p.x;
  }
  aj += __shfl_xor(aj, 4, 64); aj += __shfl_xor(aj, 8, 64);
  sl += __shfl_xor(sl, 4, 64); sl += __shfl_xor(sl, 8, 64);
  float inv = 1.f/(sl + 1e-16f);
  float m0 = __shfl(aj, 0, 16)*inv;
  float m1 = __shfl(aj, 1, 16)*inv;
  float m2 = __shfl(aj, 2, 16)*inv;
  float m3 = __shfl(aj, 3, 16)*inv;
  float xvj = m0*w0L[j*4+0] + m1*w0L[j*4+1] + m2*w0L[j*4+2] + m3*w0L[j*4+3] + bL[j];
  float hv = 0.f, u0=0.f, u1=0.f, v0=0.f, v1=0.f;
  #pragma unroll
  for (int k=0;k<16;k++){
    float vk = __shfl(xvj, k, 16);
    hv += vk * wL[j*16+k];
    u0 += vk * w1sL[(2*j)*16+k];
    u1 += vk * w1sL[(2*j+1)*16+k];
    v0 += vk * w1dL[(2*j)*16+k];
    v1 += vk * w1dL[(2*j+1)*16+k];
  }
  ((u16*)hpk)[(size_t)n*16 + j] = (u16)(pk2u(hv, 0.f) & 0xffffu);
  uh[(size_t)n*16 + j] = pk2u(u0, u1);
  vh[(size_t)n*16 + j] = pk2u(v0, v1);
  float hsp = hv*aS[j], hdp = hv*aD[j];
  #pragma unroll
  for (int ofs=1; ofs<16; ofs<<=1){
    hsp += __shfl_xor(hsp, ofs, 64);
    hdp += __shfl_xor(hdp, ofs, 64);
  }
  if (j == 0){ hs2[n]=hsp; hd2[n]=hdp; cnt[n]=0; }
}

// ---------------- k5m: edge MLP with MFMA L2/L3 + folded head + scatter -----
// = r18 (299us: LDS-staged B-frags + __syncthreads) + padded LDS strides ONLY
// (A13S 16->20, A2S 32->36; r18's 2.24e7 bank conflicts came from the
// power-of-2 strides). r19/r20 showed the per-thread scalar global B-frag
// loads cost ~60us -- reverted to cooperative LDS staging.
#define A13S 20
#define A2S  36
__global__ __launch_bounds__(256,4) void k5m(
    const int* __restrict__ ei, const float* __restrict__ ea,
    const u32* __restrict__ uh, const u32* __restrict__ vh,
    const float* __restrict__ hs2, const float* __restrict__ hd2,
    const float* w1p, const float* b1p, const float* w2p, const float* b2p,
    const float* w3p, const float* b3p, const float* w4p, const float* b4p,
    const float* We2, const float* a2e,
    const float* ew1p, const float* eb1p, const float* ew2p, const float* eb2p,
    const int* __restrict__ off, int* __restrict__ cnt, float2* __restrict__ edata,
    float* __restrict__ eout)
{
  __shared__ __align__(16) u32 a13L[4][64*A13S];   // per-wave 5120B: a1, later a3
  __shared__ __align__(16) u32 a2L[4][16*A2S];     // per-wave 2304B: a2 row-tile
  __shared__ __align__(16) uint4 b2f[4][64];    // L2 B-frags [c][lane]
  __shared__ __align__(16) uint4 b3f[4][64];    // L3 B-frags [kt*2+c][lane]
  __shared__ __align__(16) f16x2 w1eh[32*4];  __shared__ float b1L[32];
  __shared__ float b2L[64], b3L[32];
  __shared__ __align__(16) f16x2 M1h[16*16];  __shared__ float c1L[16];
  __shared__ __align__(16) f16x2 ew2h[4*8];   __shared__ float eb2L[4];
  __shared__ __align__(16) f16x2 w16w4h[16];
  __shared__ float w16L[16];  __shared__ float w16b4L;

  int tid = threadIdx.x;
  // ---- init phase A ----
  if (tid < 128){
    int j=tid>>2, kk=tid&3;
    int k0=2*kk, k1=2*kk+1;
    float v0 = (k0<6) ? w1p[j*38+16+k0] : 0.f;
    float v1 = (k1<6) ? w1p[j*38+16+k1] : 0.f;
    w1eh[tid] = pk2(v0, v1);
  }
  {
    int c = tid>>6, l = tid&63;
    int j = c*16 + (l&15), kb = (l>>4)*8;
    const float* src = w2p + j*32 + kb;
    uint4 q;
    q.x = pk2u(src[0], src[1]); q.y = pk2u(src[2], src[3]);
    q.z = pk2u(src[4], src[5]); q.w = pk2u(src[6], src[7]);
    b2f[c][l] = q;
  }
  {
    int kt = tid>>7, c = (tid>>6)&1, l = tid&63;
    int j = c*16 + (l&15), kb = kt*32 + (l>>4)*8;
    const float* src = w3p + j*64 + kb;
    uint4 q;
    q.x = pk2u(src[0], src[1]); q.y = pk2u(src[2], src[3]);
    q.z = pk2u(src[4], src[5]); q.w = pk2u(src[6], src[7]);
    b3f[kt*2+c][l] = q;
  }
  if (tid < 64) b2L[tid] = b2p[tid];
  if (tid < 32){ b1L[tid] = b1p[tid]; b3L[tid] = b3p[tid]; }
  {
    int o = tid>>4, p = tid&15;
    float m0=0.f, m1=0.f;
    #pragma unroll
    for (int q=0;q<16;q++){
      float w = ew1p[o*16+q];
      m0 += w * w4p[q*32 + 2*p];
      m1 += w * w4p[q*32 + 2*p + 1];
    }
    M1h[o*16+p] = pk2(m0, m1);
  }
  if (tid < 16){
    float acc = eb1p[tid];
    for (int q=0;q<16;q++) acc += ew1p[tid*16+q]*b4p[q];
    c1L[tid] = acc;
    float w=0.f;
    for (int j=0;j<16;j++) w += a2e[j] * We2[j*16+tid];
    w16L[tid] = w;
  }
  if (tid < 32){
    int j=tid>>3, kk=tid&7;
    ew2h[tid] = pk2(ew2p[j*16+2*kk], ew2p[j*16+2*kk+1]);
  }
  if (tid < 4) eb2L[tid] = eb2p[tid];
  __syncthreads();
  // ---- init phase B (needs w16L) ----
  if (tid < 16){
    float s0=0.f, s1=0.f;
    for (int q=0;q<16;q++){
      s0 += w16L[q]*w4p[q*32 + 2*tid];
      s1 += w16L[q]*w4p[q*32 + 2*tid + 1];
    }
    w16w4h[tid] = pk2(s0, s1);
  }
  if (tid == 0){
    float acc=0.f;
    for (int q=0;q<16;q++) acc += w16L[q]*b4p[q];
    w16b4L = acc;
  }
  __syncthreads();

  int wid = tid>>6, lane = tid&63;
  int cl = lane & 15, g = lane >> 4;
  u32* a13 = a13L[wid];
  u32* a2u = a2L[wid];
  int i = blockIdx.x*256 + tid;   // always < NE (grid exact)
  int s = clampi(ei[i]);
  int d = clampi(ei[NE + i]);

  // ---- layer 1 (per-lane, f16 dot2) ----
  u32 a1h[16];
  {
    const float2* eap = (const float2*)ea + (size_t)i*3;
    float2 e0=eap[0], e1=eap[1], e2=eap[2];
    f16x2 eh[4];
    eh[0]=pk2(e0.x,e0.y); eh[1]=pk2(e1.x,e1.y); eh[2]=pk2(e2.x,e2.y); eh[3]=pk2(0.f,0.f);
    const uint4* up = (const uint4*)(uh + (size_t)s*16);
    const uint4* vp = (const uint4*)(vh + (size_t)d*16);
    uint4 U[4], V[4];
    #pragma unroll
    for (int q=0;q<4;q++){ U[q]=up[q]; V[q]=vp[q]; }
    u32 uw[16], vw[16];
    #pragma unroll
    for (int q=0;q<4;q++){
      uw[4*q]=U[q].x; uw[4*q+1]=U[q].y; uw[4*q+2]=U[q].z; uw[4*q+3]=U[q].w;
      vw[4*q]=V[q].x; vw[4*q+1]=V[q].y; vw[4*q+2]=V[q].z; vw[4*q+3]=V[q].w;
    }
    #pragma unroll
    for (int j=0;j<16;j++){
      float t0 = b1L[2*j]   + f16lo(uw[j]) + f16lo(vw[j]);
      float t1 = b1L[2*j+1] + f16hi(uw[j]) + f16hi(vw[j]);
      #pragma unroll
      for (int kk=0;kk<4;kk++){
        t0 = dot2(eh[kk], w1eh[(2*j)*4+kk],   t0);
        t1 = dot2(eh[kk], w1eh[(2*j+1)*4+kk], t1);
      }
      a1h[j] = pk2u(fmaxf(t0,0.f), fmaxf(t1,0.f));
    }
  }
  // stage a1: row = lane, padded stride
  {
    uint4* dst = (uint4*)(a13 + lane*A13S);
    dst[0] = make_uint4(a1h[0],a1h[1],a1h[2],a1h[3]);
    dst[1] = make_uint4(a1h[4],a1h[5],a1h[6],a1h[7]);
    dst[2] = make_uint4(a1h[8],a1h[9],a1h[10],a1h[11]);
    dst[3] = make_uint4(a1h[12],a1h[13],a1h[14],a1h[15]);
  }
  // load B fragments to regs (from LDS staging)
  f16x8 fb2[4], fb3[4];
  #pragma unroll
  for (int c=0;c<4;c++) fb2[c] = __builtin_bit_cast(f16x8, b2f[c][lane]);
  #pragma unroll
  for (int q=0;q<4;q++) fb3[q] = __builtin_bit_cast(f16x8, b3f[q][lane]);
  __syncthreads();

  // ---- L2 + L3 per row-tile ----
  #pragma unroll
  for (int r=0;r<4;r++){
    __syncthreads();                 // a2 WAR from previous r
    uint4 av = *(const uint4*)(a13 + (r*16 + cl)*A13S + g*4);
    f16x8 af = __builtin_bit_cast(f16x8, av);
    _Float16* a2h_ = (_Float16*)a2u;
    #pragma unroll
    for (int c=0;c<4;c++){
      float b = b2L[c*16 + cl];
      fltx4 acc = {b,b,b,b};
      acc = __builtin_amdgcn_mfma_f32_16x16x32_f16(af, fb2[c], acc, 0, 0, 0);
      int col = c*16 + cl;
      int rowb = g*4;
      a2h_[(rowb+0)*(2*A2S) + col] = (_Float16)fmaxf(acc[0], 0.f);
      a2h_[(rowb+1)*(2*A2S) + col] = (_Float16)fmaxf(acc[1], 0.f);
      a2h_[(rowb+2)*(2*A2S) + col] = (_Float16)fmaxf(acc[2], 0.f);
      a2h_[(rowb+3)*(2*A2S) + col] = (_Float16)fmaxf(acc[3], 0.f);
    }
    __syncthreads();                 // a2 ready
    uint4 a20 = *(const uint4*)(a2u + cl*A2S + g*4);
    uint4 a21 = *(const uint4*)(a2u + cl*A2S + 16 + g*4);
    f16x8 af0 = __builtin_bit_cast(f16x8, a20);
    f16x8 af1 = __builtin_bit_cast(f16x8, a21);
    _Float16* a3w = (_Float16*)a13;
    #pragma unroll
    for (int c=0;c<2;c++){
      float b = b3L[c*16 + cl];
      fltx4 acc = {b,b,b,b};
      acc = __builtin_amdgcn_mfma_f32_16x16x32_f16(af0, fb3[0*2+c], acc, 0, 0, 0);
      acc = __builtin_amdgcn_mfma_f32_16x16x32_f16(af1, fb3[1*2+c], acc, 0, 0, 0);
      int col = c*16 + cl;
      int row = r*16 + g*4;
      a3w[(row+0)*(2*A13S) + col] = (_Float16)fmaxf(acc[0], 0.f);
      a3w[(row+1)*(2*A13S) + col] = (_Float16)fmaxf(acc[1], 0.f);
      a3w[(row+2)*(2*A13S) + col] = (_Float16)fmaxf(acc[2], 0.f);
      a3w[(row+3)*(2*A13S) + col] = (_Float16)fmaxf(acc[3], 0.f);
    }
  }
  __syncthreads();                   // a3 complete
  // readback a3 of own edge
  u32 a3h[16];
  {
    const uint4* srcp = (const uint4*)(a13 + lane*A13S);
    uint4 q0=srcp[0], q1=srcp[1], q2=srcp[2], q3=srcp[3];
    a3h[0]=q0.x; a3h[1]=q0.y; a3h[2]=q0.z; a3h[3]=q0.w;
    a3h[4]=q1.x; a3h[5]=q1.y; a3h[6]=q1.z; a3h[7]=q1.w;
    a3h[8]=q2.x; a3h[9]=q2.y; a3h[10]=q2.z; a3h[11]=q2.w;
    a3h[12]=q3.x; a3h[13]=q3.y; a3h[14]=q3.z; a3h[15]=q3.w;
  }
  // ---- folded L4 + head1: t = relu(M1.a3 + c1) ----
  f16x2 th[8];
  #pragma unroll
  for (int o=0;o<8;o++){
    float t0 = c1L[2*o], t1 = c1L[2*o+1];
    #pragma unroll
    for (int kp=0;kp<16;kp++){
      f16x2 a = __builtin_bit_cast(f16x2, a3h[kp]);
      t0 = dot2(a, M1h[(2*o)*16+kp],   t0);
      t1 = dot2(a, M1h[(2*o+1)*16+kp], t1);
    }
    th[o] = pk2(fmaxf(t0,0.f), fmaxf(t1,0.f));
  }
  // ---- head2 + log_softmax(4) ----
  float y0 = eb2L[0], y1 = eb2L[1], y2 = eb2L[2], y3 = eb2L[3];
  #pragma unroll
  for (int kk=0;kk<8;kk++){
    y0 = dot2(th[kk], ew2h[0*8+kk], y0);
    y1 = dot2(th[kk], ew2h[1*8+kk], y1);
    y2 = dot2(th[kk], ew2h[2*8+kk], y2);
    y3 = dot2(th[kk], ew2h[3*8+kk], y3);
  }
  y0 = fmaxf(y0,0.f); y1 = fmaxf(y1,0.f); y2 = fmaxf(y2,0.f); y3 = fmaxf(y3,0.f);
  float m = fmaxf(fmaxf(y0,y1), fmaxf(y2,y3));
  float l = m + __logf(__expf(y0-m)+__expf(y1-m)+__expf(y2-m)+__expf(y3-m));
  float4 eo; eo.x = y0-l; eo.y = y1-l; eo.z = y2-l; eo.w = y3-l;
  ((float4*)eout)[i] = eo;

  // ---- conv2 alpha via folded w16w4 ----
  float al = hs2[s] + hd2[d] + w16b4L;
  #pragma unroll
  for (int kp=0;kp<16;kp++){
    f16x2 a = __builtin_bit_cast(f16x2, a3h[kp]);
    al = dot2(a, w16w4h[kp], al);
  }
  al = al > 0.f ? al : 0.2f*al;
  float ex = __expf(al);
  int pos = off[d] + atomicAdd(&cnt[d], 1);
  edata[pos] = make_float2(ex, __int_as_float(s));
}

// ---------------- kagg2: conv2 CSR reduce + fused node head ----------------
__global__ __launch_bounds__(256,8) void kagg2(const float2* __restrict__ edata,
    const int* __restrict__ off, const u16* __restrict__ hpk,
    const float* __restrict__ c2b,
    const float* __restrict__ w1p, const float* __restrict__ b1p,
    const float* __restrict__ w2p, const float* __restrict__ b2p,
    float* __restrict__ nout, int* __restrict__ cnt)
{
  __shared__ float w1L[256], cb[16], b1L[16], w2L[32], b2L[2];
  int tid = threadIdx.x;
  w1L[tid] = w1p[tid];
  if (tid < 16){ cb[tid] = c2b[tid]; b1L[tid] = b1p[tid]; }
  if (tid < 32) w2L[tid] = w2p[tid];
  if (tid < 2)  b2L[tid] = b2p[tid];
  __syncthreads();
  int t = blockIdx.x*256 + tid;
  int n = t >> 6;
  int l = t & 63;
  if (n >= NN) return;
  int j = l & 15, ks = l >> 4;
  int beg = off[n], end = off[n+1];
  float aj = 0.f, sl = 0.f;
  for (int k = beg + ks; k < end; k += 4){
    float2 p = edata[k];
    int src = __float_as_int(p.y);
    aj += p.x * f16u(hpk[(size_t)src*16 + j]);
    sl += p.x;
  }
  aj += __shfl_xor(aj, 16, 64); aj += __shfl_xor(aj, 32, 64);
  sl += __shfl_xor(sl, 16, 64); sl += __shfl_xor(sl, 32, 64);
  float inv = 1.f/(sl + 1e-16f);
  float vj = aj*inv + cb[j];
  float tj = b1L[j];
  #pragma unroll
  for (int k=0;k<16;k++){
    float vk = __shfl(vj, k, 16);
    tj += vk * w1L[j*16 + k];
  }
  tj = fmaxf(tj, 0.f);
  float p0 = tj * w2L[j];
  float p1 = tj * w2L[16 + j];
  #pragma unroll
  for (int ofs=1; ofs<16; ofs<<=1){
    p0 += __shfl_xor(p0, ofs, 64);
    p1 += __shfl_xor(p1, ofs, 64);
  }
  if (l == 0){
    float y0 = fmaxf(p0 + b2L[0], 0.f);
    float y1 = fmaxf(p1 + b2L[1], 0.f);
    float m = fmaxf(y0, y1);
    float lg = m + __logf(__expf(y0-m) + __expf(y1-m));
    float2 no; no.x = y0-lg; no.y = y1-lg;
    ((float2*)nout)[n] = no;
    cnt[n] = 0;
  }
}

extern "C" void kernel_launch(void* const* d_in, const int* in_sizes, int n_in,
                              void* d_out, int out_size, void* d_ws, size_t ws_size,
                              hipStream_t stream)
{
  const float* x  = (const float*)d_in[0];
  const int* ei   = (const int*)d_in[1];
  const float* ea = (const float*)d_in[2];
  const float* c1Wx = (const float*)d_in[3];
  const float* c1We = (const float*)d_in[4];
  const float* c1as = (const float*)d_in[5];
  const float* c1ad = (const float*)d_in[6];
  const float* c1ae = (const float*)d_in[7];
  const float* c1b  = (const float*)d_in[8];
  const float* e1w1 = (const float*)d_in[9];
  const float* e1b1 = (const float*)d_in[10];
  const float* e1w2 = (const float*)d_in[11];
  const float* e1b2 = (const float*)d_in[12];
  const float* e1w3 = (const float*)d_in[13];
  const float* e1b3 = (const float*)d_in[14];
  const float* e1w4 = (const float*)d_in[15];
  const float* e1b4 = (const float*)d_in[16];
  const float* c2Wx = (const float*)d_in[17];
  const float* c2We = (const float*)d_in[18];
  const float* c2as = (const float*)d_in[19];
  const float* c2ad = (const float*)d_in[20];
  const float* c2ae = (const float*)d_in[21];
  const float* c2b  = (const float*)d_in[22];
  const float* nlw1 = (const float*)d_in[23];
  const float* nlb1 = (const float*)d_in[24];
  const float* nlw2 = (const float*)d_in[25];
  const float* nlb2 = (const float*)d_in[26];
  const float* elw1 = (const float*)d_in[27];
  const float* elb1 = (const float*)d_in[28];
  const float* elw2 = (const float*)d_in[29];
  const float* elb2 = (const float*)d_in[30];

  float* ws = (float*)d_ws;
  const size_t N = NN;
  int* off   = (int*)ws;                     // N+8
  int* cnt   = (int*)ws + (N + 8);           // N
  int* bsum  = (int*)ws + (2*N + 8);         // 128
  int* boff  = (int*)ws + (2*N + 136);       // 128
  u32* hpk   = (u32*)(ws + 2*N + 264);       // 8N u32 (f16x2-packed h2)
  float* hs  = ws + 10*N + 264;              // N
  float* hd  = hs + N;                       // N
  u32* uh    = (u32*)(hd + N);               // 16N u32
  u32* vh    = uh + 16*N;                    // 16N u32
  float2* edata = (float2*)(vh + 16*N);      // NE float2

  float* nout = (float*)d_out;               // [100000, 2]
  float* eout = (float*)d_out + 200000;      // [3200000, 4]

  const int GE = (NE + 255)/256;
  const int GN = (NN + 255)/256;

  (void)hipMemsetAsync(cnt, 0, N*sizeof(int), stream);
  khist<<<GE, 256, 0, stream>>>(ei, cnt);
  kscanA<<<NB, 1024, 0, stream>>>(cnt, bsum);
  kscanB<<<1, 64, 0, stream>>>(bsum, boff, off + NN);
  kscanC<<<NB, 1024, 0, stream>>>(cnt, boff, off);
  k1<<<GN, 256, 0, stream>>>(x, c1Wx, c1as, c1ad, hs, hd);
  k2a<<<GE, 256, 0, stream>>>(ei, ea, c1We, c1ae, hs, hd, off, cnt, edata);
  k34<<<(NN*16 + 255)/256, 256, 0, stream>>>(edata, off, x,
      c1b, c1Wx, c2Wx, c2as, c2ad, e1w1, hpk, hs, hd, uh, vh, cnt);
  k5m<<<GE, 256, 0, stream>>>(ei, ea, uh, vh, hs, hd,
      e1w1, e1b1, e1w2, e1b2, e1w3, e1b3, e1w4, e1b4,
      c2We, c2ae, elw1, elb1, elw2, elb2,
      off, cnt, edata, eout);
  kagg2<<<(NN*64 + 255)/256, 256, 0, stream>>>(edata, off, (const u16*)hpk,
      c2b, nlw1, nlb1, nlw2, nlb2, nout, cnt);
}

// Round 22
// 701.394 us; speedup vs baseline: 1.1328x; 1.0593x over previous
//
#include <hip/hip_runtime.h>

#define NN 100000
#define NE 3200000
#define NB 98   // ceil(NN/1024)

typedef unsigned int u32;
typedef unsigned short u16;
typedef _Float16 f16x2 __attribute__((ext_vector_type(2)));
typedef _Float16 f16x8 __attribute__((ext_vector_type(8)));
typedef float fltx4 __attribute__((ext_vector_type(4)));
typedef __fp16 fp16v2 __attribute__((ext_vector_type(2)));

__device__ __forceinline__ int clampi(int s){
  s = s < 0 ? 0 : s;
  return s >= NN ? NN-1 : s;
}

__device__ __forceinline__ f16x2 pk2(float x, float y){
  fp16v2 r = __builtin_amdgcn_cvt_pkrtz(x, y);
  return __builtin_bit_cast(f16x2, r);
}
__device__ __forceinline__ u32 pk2u(float x, float y){
  return __builtin_bit_cast(u32, pk2(x, y));
}
__device__ __forceinline__ float dot2(f16x2 a, f16x2 b, float c){
  return __builtin_amdgcn_fdot2(a, b, c, false);
}
__device__ __forceinline__ float f16lo(u32 w){
  __fp16 h = __builtin_bit_cast(__fp16, (u16)(w & 0xffffu));
  return (float)h;
}
__device__ __forceinline__ float f16hi(u32 w){
  __fp16 h = __builtin_bit_cast(__fp16, (u16)(w >> 16));
  return (float)h;
}
__device__ __forceinline__ float f16u(u16 w){
  __fp16 h = __builtin_bit_cast(__fp16, w);
  return (float)h;
}

// ---------------- khist: cnt[d]++ ------------------------------------------
__global__ __launch_bounds__(256,8) void khist(const int* __restrict__ ei, int* __restrict__ cnt){
  int i = blockIdx.x*256 + threadIdx.x;
  if (i >= NE) return;
  atomicAdd(&cnt[clampi(ei[NE+i])], 1);
}

// ---------------- kscanA: per-block sums of cnt -----------------------------
__global__ __launch_bounds__(1024) void kscanA(const int* __restrict__ cnt, int* __restrict__ bsum){
  __shared__ int wsum[16];
  int tid = threadIdx.x;
  int i = blockIdx.x*1024 + tid;
  int x = (i < NN) ? cnt[i] : 0;
  #pragma unroll
  for (int ofs = 1; ofs < 64; ofs <<= 1) x += __shfl_xor(x, ofs, 64);
  if ((tid & 63) == 0) wsum[tid >> 6] = x;
  __syncthreads();
  if (tid == 0){
    int t = 0;
    #pragma unroll
    for (int k = 0; k < 16; k++) t += wsum[k];
    bsum[blockIdx.x] = t;
  }
}

// ---------------- kscanB: scan the 98 block sums ----------------------------
__global__ void kscanB(const int* __restrict__ bsum, int* __restrict__ boff, int* __restrict__ offN){
  if (threadIdx.x == 0){
    int c = 0;
    for (int b = 0; b < NB; b++){ boff[b] = c; c += bsum[b]; }
    offN[0] = c;
  }
}

// ---------------- kscanC: block-local scan + offset; cnt = 0 ----------------
__global__ __launch_bounds__(1024) void kscanC(int* __restrict__ cnt, const int* __restrict__ boff,
                                               int* __restrict__ off){
  __shared__ int wsum[16];
  int tid = threadIdx.x;
  int i = blockIdx.x*1024 + tid;
  int v = (i < NN) ? cnt[i] : 0;
  int x = v;
  #pragma unroll
  for (int ofs = 1; ofs < 64; ofs <<= 1){
    int t = __shfl_up(x, ofs, 64);
    if ((tid & 63) >= ofs) x += t;
  }
  if ((tid & 63) == 63) wsum[tid >> 6] = x;
  __syncthreads();
  if (tid < 16){
    int y = wsum[tid];
    #pragma unroll
    for (int ofs = 1; ofs < 16; ofs <<= 1){
      int t = __shfl_up(y, ofs, 64);
      if (tid >= ofs) y += t;
    }
    wsum[tid] = y;
  }
  __syncthreads();
  int wb = (tid >= 64) ? wsum[(tid >> 6) - 1] : 0;
  if (i < NN){ off[i] = boff[blockIdx.x] + wb + x - v; cnt[i] = 0; }
}

// ---------------- k1: hs1 = (Wx x).a_src ; hd1 = (Wx x).a_dst ---------------
__global__ __launch_bounds__(256,4) void k1(const float* __restrict__ x,
    const float* __restrict__ Wx, const float* __restrict__ asrc, const float* __restrict__ adst,
    float* __restrict__ hs1, float* __restrict__ hd1)
{
  __shared__ float wL[64], aS[16], aD[16];
  int tid = threadIdx.x;
  if (tid < 64) wL[tid] = Wx[tid];
  if (tid < 16){ aS[tid] = asrc[tid]; aD[tid] = adst[tid]; }
  __syncthreads();
  int n = blockIdx.x*256 + tid;
  if (n >= NN) return;
  float4 xr = ((const float4*)x)[n];
  float hs=0.f, hd=0.f;
  #pragma unroll
  for (int j=0;j<16;j++){
    float h = xr.x*wL[j*4+0] + xr.y*wL[j*4+1] + xr.z*wL[j*4+2] + xr.w*wL[j*4+3];
    hs += h*aS[j]; hd += h*aD[j];
  }
  hs1[n]=hs; hd1[n]=hd;
}

// ---------------- k2a: alpha1 -> CSR scatter; records slot in epos ----------
__global__ __launch_bounds__(256,8) void k2a(const int* __restrict__ ei,
    const float* __restrict__ ea, const float* __restrict__ We, const float* __restrict__ aedge,
    const float* __restrict__ hs1, const float* __restrict__ hd1,
    const int* __restrict__ off, int* __restrict__ cnt, float2* __restrict__ edata,
    int* __restrict__ epos)
{
  __shared__ float w6[6];
  int tid = threadIdx.x;
  if (tid < 6){
    float acc = 0.f;
    for (int j=0;j<16;j++) acc += aedge[j] * We[j*6+tid];
    w6[tid] = acc;
  }
  __syncthreads();
  int i = blockIdx.x*256 + tid;
  if (i >= NE) return;
  int s = clampi(ei[i]);
  int d = clampi(ei[NE + i]);
  const float2* eap = (const float2*)ea + (size_t)i*3;
  float2 u0 = eap[0], u1 = eap[1], u2 = eap[2];
  float al = hs1[s] + hd1[d]
    + u0.x*w6[0] + u0.y*w6[1] + u1.x*w6[2]
    + u1.y*w6[3] + u2.x*w6[4] + u2.y*w6[5];
  al = al > 0.f ? al : 0.2f*al;
  float ex = __expf(al);
  int pos = off[d] + atomicAdd(&cnt[d], 1);
  edata[pos] = make_float2(ex, __int_as_float(s));
  epos[i] = pos;
}

// ---------------- k34: conv1 CSR reduce + node transform --------------------
__global__ __launch_bounds__(256,8) void k34(const float2* __restrict__ edata,
    const int* __restrict__ off, const float* __restrict__ x,
    const float* __restrict__ c1b, const float* __restrict__ Wx1, const float* __restrict__ Wx2,
    const float* __restrict__ a2s, const float* __restrict__ a2d,
    const float* __restrict__ w1p,
    u32* __restrict__ hpk, float* __restrict__ hs2, float* __restrict__ hd2,
    u32* __restrict__ uh, u32* __restrict__ vh)
{
  __shared__ float w0L[64], bL[16], wL[256], aS[16], aD[16];
  __shared__ float w1sL[32*16], w1dL[32*16];
  int tid = threadIdx.x;
  wL[tid] = Wx2[tid];
  if (tid < 64) w0L[tid] = Wx1[tid];
  if (tid < 16){ bL[tid]=c1b[tid]; aS[tid]=a2s[tid]; aD[tid]=a2d[tid]; }
  for (int idx=tid; idx<512; idx+=256){
    int j=idx>>4, k=idx&15;
    w1sL[idx] = w1p[j*38+k];
    w1dL[idx] = w1p[j*38+22+k];
  }
  __syncthreads();
  int t = blockIdx.x*256 + tid;
  int n = t >> 4;
  int j = t & 15;
  if (n >= NN) return;
  int f = j & 3, ks = j >> 2;
  int beg = off[n], end = off[n+1];
  float aj = 0.f, sl = 0.f;
  for (int k = beg + ks; k < end; k += 4){
    float2 p = edata[k];
    int src = __float_as_int(p.y);
    aj += p.x * x[(size_t)src*4 + f];
    sl += p.x;
  }
  aj += __shfl_xor(aj, 4, 64); aj += __shfl_xor(aj, 8, 64);
  sl += __shfl_xor(sl, 4, 64); sl += __shfl_xor(sl, 8, 64);
  float inv = 1.f/(sl + 1e-16f);
  float m0 = __shfl(aj, 0, 16)*inv;
  float m1 = __shfl(aj, 1, 16)*inv;
  float m2 = __shfl(aj, 2, 16)*inv;
  float m3 = __shfl(aj, 3, 16)*inv;
  float xvj = m0*w0L[j*4+0] + m1*w0L[j*4+1] + m2*w0L[j*4+2] + m3*w0L[j*4+3] + bL[j];
  float hv = 0.f, u0=0.f, u1=0.f, v0=0.f, v1=0.f;
  #pragma unroll
  for (int k=0;k<16;k++){
    float vk = __shfl(xvj, k, 16);
    hv += vk * wL[j*16+k];
    u0 += vk * w1sL[(2*j)*16+k];
    u1 += vk * w1sL[(2*j+1)*16+k];
    v0 += vk * w1dL[(2*j)*16+k];
    v1 += vk * w1dL[(2*j+1)*16+k];
  }
  ((u16*)hpk)[(size_t)n*16 + j] = (u16)(pk2u(hv, 0.f) & 0xffffu);
  uh[(size_t)n*16 + j] = pk2u(u0, u1);
  vh[(size_t)n*16 + j] = pk2u(v0, v1);
  float hsp = hv*aS[j], hdp = hv*aD[j];
  #pragma unroll
  for (int ofs=1; ofs<16; ofs<<=1){
    hsp += __shfl_xor(hsp, ofs, 64);
    hdp += __shfl_xor(hdp, ofs, 64);
  }
  if (j == 0){ hs2[n]=hsp; hd2[n]=hdp; }
}

// ---------------- k5m: edge MLP with MFMA L2/L3 + folded head + scatter -----
// r18/r21 config (299us floor). Conv2 scatter now uses epos[i] (slot recorded
// by k2a) -- removes 3.2M contended atomics + off[d] gather from this kernel.
#define A13S 20
#define A2S  36
__global__ __launch_bounds__(256,4) void k5m(
    const int* __restrict__ ei, const float* __restrict__ ea,
    const u32* __restrict__ uh, const u32* __restrict__ vh,
    const float* __restrict__ hs2, const float* __restrict__ hd2,
    const float* w1p, const float* b1p, const float* w2p, const float* b2p,
    const float* w3p, const float* b3p, const float* w4p, const float* b4p,
    const float* We2, const float* a2e,
    const float* ew1p, const float* eb1p, const float* ew2p, const float* eb2p,
    const int* __restrict__ epos, float2* __restrict__ edata,
    float* __restrict__ eout)
{
  __shared__ __align__(16) u32 a13L[4][64*A13S];   // per-wave 5120B: a1, later a3
  __shared__ __align__(16) u32 a2L[4][16*A2S];     // per-wave 2304B: a2 row-tile
  __shared__ __align__(16) uint4 b2f[4][64];    // L2 B-frags [c][lane]
  __shared__ __align__(16) uint4 b3f[4][64];    // L3 B-frags [kt*2+c][lane]
  __shared__ __align__(16) f16x2 w1eh[32*4];  __shared__ float b1L[32];
  __shared__ float b2L[64], b3L[32];
  __shared__ __align__(16) f16x2 M1h[16*16];  __shared__ float c1L[16];
  __shared__ __align__(16) f16x2 ew2h[4*8];   __shared__ float eb2L[4];
  __shared__ __align__(16) f16x2 w16w4h[16];
  __shared__ float w16L[16];  __shared__ float w16b4L;

  int tid = threadIdx.x;
  // ---- init phase A ----
  if (tid < 128){
    int j=tid>>2, kk=tid&3;
    int k0=2*kk, k1=2*kk+1;
    float v0 = (k0<6) ? w1p[j*38+16+k0] : 0.f;
    float v1 = (k1<6) ? w1p[j*38+16+k1] : 0.f;
    w1eh[tid] = pk2(v0, v1);
  }
  {
    int c = tid>>6, l = tid&63;
    int j = c*16 + (l&15), kb = (l>>4)*8;
    const float* src = w2p + j*32 + kb;
    uint4 q;
    q.x = pk2u(src[0], src[1]); q.y = pk2u(src[2], src[3]);
    q.z = pk2u(src[4], src[5]); q.w = pk2u(src[6], src[7]);
    b2f[c][l] = q;
  }
  {
    int kt = tid>>7, c = (tid>>6)&1, l = tid&63;
    int j = c*16 + (l&15), kb = kt*32 + (l>>4)*8;
    const float* src = w3p + j*64 + kb;
    uint4 q;
    q.x = pk2u(src[0], src[1]); q.y = pk2u(src[2], src[3]);
    q.z = pk2u(src[4], src[5]); q.w = pk2u(src[6], src[7]);
    b3f[kt*2+c][l] = q;
  }
  if (tid < 64) b2L[tid] = b2p[tid];
  if (tid < 32){ b1L[tid] = b1p[tid]; b3L[tid] = b3p[tid]; }
  {
    int o = tid>>4, p = tid&15;
    float m0=0.f, m1=0.f;
    #pragma unroll
    for (int q=0;q<16;q++){
      float w = ew1p[o*16+q];
      m0 += w * w4p[q*32 + 2*p];
      m1 += w * w4p[q*32 + 2*p + 1];
    }
    M1h[o*16+p] = pk2(m0, m1);
  }
  if (tid < 16){
    float acc = eb1p[tid];
    for (int q=0;q<16;q++) acc += ew1p[tid*16+q]*b4p[q];
    c1L[tid] = acc;
    float w=0.f;
    for (int j=0;j<16;j++) w += a2e[j] * We2[j*16+tid];
    w16L[tid] = w;
  }
  if (tid < 32){
    int j=tid>>3, kk=tid&7;
    ew2h[tid] = pk2(ew2p[j*16+2*kk], ew2p[j*16+2*kk+1]);
  }
  if (tid < 4) eb2L[tid] = eb2p[tid];
  __syncthreads();
  // ---- init phase B (needs w16L) ----
  if (tid < 16){
    float s0=0.f, s1=0.f;
    for (int q=0;q<16;q++){
      s0 += w16L[q]*w4p[q*32 + 2*tid];
      s1 += w16L[q]*w4p[q*32 + 2*tid + 1];
    }
    w16w4h[tid] = pk2(s0, s1);
  }
  if (tid == 0){
    float acc=0.f;
    for (int q=0;q<16;q++) acc += w16L[q]*b4p[q];
    w16b4L = acc;
  }
  __syncthreads();

  int wid = tid>>6, lane = tid&63;
  int cl = lane & 15, g = lane >> 4;
  u32* a13 = a13L[wid];
  u32* a2u = a2L[wid];
  int i = blockIdx.x*256 + tid;   // always < NE (grid exact)
  int s = clampi(ei[i]);
  int d = clampi(ei[NE + i]);

  // ---- layer 1 (per-lane, f16 dot2) ----
  u32 a1h[16];
  {
    const float2* eap = (const float2*)ea + (size_t)i*3;
    float2 e0=eap[0], e1=eap[1], e2=eap[2];
    f16x2 eh[4];
    eh[0]=pk2(e0.x,e0.y); eh[1]=pk2(e1.x,e1.y); eh[2]=pk2(e2.x,e2.y); eh[3]=pk2(0.f,0.f);
    const uint4* up = (const uint4*)(uh + (size_t)s*16);
    const uint4* vp = (const uint4*)(vh + (size_t)d*16);
    uint4 U[4], V[4];
    #pragma unroll
    for (int q=0;q<4;q++){ U[q]=up[q]; V[q]=vp[q]; }
    u32 uw[16], vw[16];
    #pragma unroll
    for (int q=0;q<4;q++){
      uw[4*q]=U[q].x; uw[4*q+1]=U[q].y; uw[4*q+2]=U[q].z; uw[4*q+3]=U[q].w;
      vw[4*q]=V[q].x; vw[4*q+1]=V[q].y; vw[4*q+2]=V[q].z; vw[4*q+3]=V[q].w;
    }
    #pragma unroll
    for (int j=0;j<16;j++){
      float t0 = b1L[2*j]   + f16lo(uw[j]) + f16lo(vw[j]);
      float t1 = b1L[2*j+1] + f16hi(uw[j]) + f16hi(vw[j]);
      #pragma unroll
      for (int kk=0;kk<4;kk++){
        t0 = dot2(eh[kk], w1eh[(2*j)*4+kk],   t0);
        t1 = dot2(eh[kk], w1eh[(2*j+1)*4+kk], t1);
      }
      a1h[j] = pk2u(fmaxf(t0,0.f), fmaxf(t1,0.f));
    }
  }
  // stage a1: row = lane, padded stride
  {
    uint4* dst = (uint4*)(a13 + lane*A13S);
    dst[0] = make_uint4(a1h[0],a1h[1],a1h[2],a1h[3]);
    dst[1] = make_uint4(a1h[4],a1h[5],a1h[6],a1h[7]);
    dst[2] = make_uint4(a1h[8],a1h[9],a1h[10],a1h[11]);
    dst[3] = make_uint4(a1h[12],a1h[13],a1h[14],a1h[15]);
  }
  // load B fragments to regs (from LDS staging)
  f16x8 fb2[4], fb3[4];
  #pragma unroll
  for (int c=0;c<4;c++) fb2[c] = __builtin_bit_cast(f16x8, b2f[c][lane]);
  #pragma unroll
  for (int q=0;q<4;q++) fb3[q] = __builtin_bit_cast(f16x8, b3f[q][lane]);
  __syncthreads();

  // ---- L2 + L3 per row-tile ----
  #pragma unroll
  for (int r=0;r<4;r++){
    __syncthreads();                 // a2 WAR from previous r
    uint4 av = *(const uint4*)(a13 + (r*16 + cl)*A13S + g*4);
    f16x8 af = __builtin_bit_cast(f16x8, av);
    _Float16* a2h_ = (_Float16*)a2u;
    #pragma unroll
    for (int c=0;c<4;c++){
      float b = b2L[c*16 + cl];
      fltx4 acc = {b,b,b,b};
      acc = __builtin_amdgcn_mfma_f32_16x16x32_f16(af, fb2[c], acc, 0, 0, 0);
      int col = c*16 + cl;
      int rowb = g*4;
      a2h_[(rowb+0)*(2*A2S) + col] = (_Float16)fmaxf(acc[0], 0.f);
      a2h_[(rowb+1)*(2*A2S) + col] = (_Float16)fmaxf(acc[1], 0.f);
      a2h_[(rowb+2)*(2*A2S) + col] = (_Float16)fmaxf(acc[2], 0.f);
      a2h_[(rowb+3)*(2*A2S) + col] = (_Float16)fmaxf(acc[3], 0.f);
    }
    __syncthreads();                 // a2 ready
    uint4 a20 = *(const uint4*)(a2u + cl*A2S + g*4);
    uint4 a21 = *(const uint4*)(a2u + cl*A2S + 16 + g*4);
    f16x8 af0 = __builtin_bit_cast(f16x8, a20);
    f16x8 af1 = __builtin_bit_cast(f16x8, a21);
    _Float16* a3w = (_Float16*)a13;
    #pragma unroll
    for (int c=0;c<2;c++){
      float b = b3L[c*16 + cl];
      fltx4 acc = {b,b,b,b};
      acc = __builtin_amdgcn_mfma_f32_16x16x32_f16(af0, fb3[0*2+c], acc, 0, 0, 0);
      acc = __builtin_amdgcn_mfma_f32_16x16x32_f16(af1, fb3[1*2+c], acc, 0, 0, 0);
      int col = c*16 + cl;
      int row = r*16 + g*4;
      a3w[(row+0)*(2*A13S) + col] = (_Float16)fmaxf(acc[0], 0.f);
      a3w[(row+1)*(2*A13S) + col] = (_Float16)fmaxf(acc[1], 0.f);
      a3w[(row+2)*(2*A13S) + col] = (_Float16)fmaxf(acc[2], 0.f);
      a3w[(row+3)*(2*A13S) + col] = (_Float16)fmaxf(acc[3], 0.f);
    }
  }
  __syncthreads();                   // a3 complete
  // readback a3 of own edge
  u32 a3h[16];
  {
    const uint4* srcp = (const uint4*)(a13 + lane*A13S);
    uint4 q0=srcp[0], q1=srcp[1], q2=srcp[2], q3=srcp[3];
    a3h[0]=q0.x; a3h[1]=q0.y; a3h[2]=q0.z; a3h[3]=q0.w;
    a3h[4]=q1.x; a3h[5]=q1.y; a3h[6]=q1.z; a3h[7]=q1.w;
    a3h[8]=q2.x; a3h[9]=q2.y; a3h[10]=q2.z; a3h[11]=q2.w;
    a3h[12]=q3.x; a3h[13]=q3.y; a3h[14]=q3.z; a3h[15]=q3.w;
  }
  // ---- folded L4 + head1: t = relu(M1.a3 + c1) ----
  f16x2 th[8];
  #pragma unroll
  for (int o=0;o<8;o++){
    float t0 = c1L[2*o], t1 = c1L[2*o+1];
    #pragma unroll
    for (int kp=0;kp<16;kp++){
      f16x2 a = __builtin_bit_cast(f16x2, a3h[kp]);
      t0 = dot2(a, M1h[(2*o)*16+kp],   t0);
      t1 = dot2(a, M1h[(2*o+1)*16+kp], t1);
    }
    th[o] = pk2(fmaxf(t0,0.f), fmaxf(t1,0.f));
  }
  // ---- head2 + log_softmax(4) ----
  float y0 = eb2L[0], y1 = eb2L[1], y2 = eb2L[2], y3 = eb2L[3];
  #pragma unroll
  for (int kk=0;kk<8;kk++){
    y0 = dot2(th[kk], ew2h[0*8+kk], y0);
    y1 = dot2(th[kk], ew2h[1*8+kk], y1);
    y2 = dot2(th[kk], ew2h[2*8+kk], y2);
    y3 = dot2(th[kk], ew2h[3*8+kk], y3);
  }
  y0 = fmaxf(y0,0.f); y1 = fmaxf(y1,0.f); y2 = fmaxf(y2,0.f); y3 = fmaxf(y3,0.f);
  float m = fmaxf(fmaxf(y0,y1), fmaxf(y2,y3));
  float l = m + __logf(__expf(y0-m)+__expf(y1-m)+__expf(y2-m)+__expf(y3-m));
  float4 eo; eo.x = y0-l; eo.y = y1-l; eo.z = y2-l; eo.w = y3-l;
  ((float4*)eout)[i] = eo;

  // ---- conv2 alpha via folded w16w4; scatter to precomputed slot ----
  float al = hs2[s] + hd2[d] + w16b4L;
  #pragma unroll
  for (int kp=0;kp<16;kp++){
    f16x2 a = __builtin_bit_cast(f16x2, a3h[kp]);
    al = dot2(a, w16w4h[kp], al);
  }
  al = al > 0.f ? al : 0.2f*al;
  float ex = __expf(al);
  edata[epos[i]] = make_float2(ex, __int_as_float(s));
}

// ---------------- kagg2: conv2 CSR reduce + fused node head ----------------
__global__ __launch_bounds__(256,8) void kagg2(const float2* __restrict__ edata,
    const int* __restrict__ off, const u16* __restrict__ hpk,
    const float* __restrict__ c2b,
    const float* __restrict__ w1p, const float* __restrict__ b1p,
    const float* __restrict__ w2p, const float* __restrict__ b2p,
    float* __restrict__ nout)
{
  __shared__ float w1L[256], cb[16], b1L[16], w2L[32], b2L[2];
  int tid = threadIdx.x;
  w1L[tid] = w1p[tid];
  if (tid < 16){ cb[tid] = c2b[tid]; b1L[tid] = b1p[tid]; }
  if (tid < 32) w2L[tid] = w2p[tid];
  if (tid < 2)  b2L[tid] = b2p[tid];
  __syncthreads();
  int t = blockIdx.x*256 + tid;
  int n = t >> 6;
  int l = t & 63;
  if (n >= NN) return;
  int j = l & 15, ks = l >> 4;
  int beg = off[n], end = off[n+1];
  float aj = 0.f, sl = 0.f;
  for (int k = beg + ks; k < end; k += 4){
    float2 p = edata[k];
    int src = __float_as_int(p.y);
    aj += p.x * f16u(hpk[(size_t)src*16 + j]);
    sl += p.x;
  }
  aj += __shfl_xor(aj, 16, 64); aj += __shfl_xor(aj, 32, 64);
  sl += __shfl_xor(sl, 16, 64); sl += __shfl_xor(sl, 32, 64);
  float inv = 1.f/(sl + 1e-16f);
  float vj = aj*inv + cb[j];
  float tj = b1L[j];
  #pragma unroll
  for (int k=0;k<16;k++){
    float vk = __shfl(vj, k, 16);
    tj += vk * w1L[j*16 + k];
  }
  tj = fmaxf(tj, 0.f);
  float p0 = tj * w2L[j];
  float p1 = tj * w2L[16 + j];
  #pragma unroll
  for (int ofs=1; ofs<16; ofs<<=1){
    p0 += __shfl_xor(p0, ofs, 64);
    p1 += __shfl_xor(p1, ofs, 64);
  }
  if (l == 0){
    float y0 = fmaxf(p0 + b2L[0], 0.f);
    float y1 = fmaxf(p1 + b2L[1], 0.f);
    float m = fmaxf(y0, y1);
    float lg = m + __logf(__expf(y0-m) + __expf(y1-m));
    float2 no; no.x = y0-lg; no.y = y1-lg;
    ((float2*)nout)[n] = no;
  }
}

extern "C" void kernel_launch(void* const* d_in, const int* in_sizes, int n_in,
                              void* d_out, int out_size, void* d_ws, size_t ws_size,
                              hipStream_t stream)
{
  const float* x  = (const float*)d_in[0];
  const int* ei   = (const int*)d_in[1];
  const float* ea = (const float*)d_in[2];
  const float* c1Wx = (const float*)d_in[3];
  const float* c1We = (const float*)d_in[4];
  const float* c1as = (const float*)d_in[5];
  const float* c1ad = (const float*)d_in[6];
  const float* c1ae = (const float*)d_in[7];
  const float* c1b  = (const float*)d_in[8];
  const float* e1w1 = (const float*)d_in[9];
  const float* e1b1 = (const float*)d_in[10];
  const float* e1w2 = (const float*)d_in[11];
  const float* e1b2 = (const float*)d_in[12];
  const float* e1w3 = (const float*)d_in[13];
  const float* e1b3 = (const float*)d_in[14];
  const float* e1w4 = (const float*)d_in[15];
  const float* e1b4 = (const float*)d_in[16];
  const float* c2Wx = (const float*)d_in[17];
  const float* c2We = (const float*)d_in[18];
  const float* c2as = (const float*)d_in[19];
  const float* c2ad = (const float*)d_in[20];
  const float* c2ae = (const float*)d_in[21];
  const float* c2b  = (const float*)d_in[22];
  const float* nlw1 = (const float*)d_in[23];
  const float* nlb1 = (const float*)d_in[24];
  const float* nlw2 = (const float*)d_in[25];
  const float* nlb2 = (const float*)d_in[26];
  const float* elw1 = (const float*)d_in[27];
  const float* elb1 = (const float*)d_in[28];
  const float* elw2 = (const float*)d_in[29];
  const float* elb2 = (const float*)d_in[30];

  float* ws = (float*)d_ws;
  const size_t N = NN;
  int* off   = (int*)ws;                     // N+8
  int* cnt   = (int*)ws + (N + 8);           // N
  int* bsum  = (int*)ws + (2*N + 8);         // 128
  int* boff  = (int*)ws + (2*N + 136);       // 128
  u32* hpk   = (u32*)(ws + 2*N + 264);       // 8N u32 (f16x2-packed h2)
  float* hs  = ws + 10*N + 264;              // N
  float* hd  = hs + N;                       // N
  u32* uh    = (u32*)(hd + N);               // 16N u32
  u32* vh    = uh + 16*N;                    // 16N u32
  float2* edata = (float2*)(vh + 16*N);      // NE float2
  int* epos  = (int*)(edata + NE);           // NE int

  float* nout = (float*)d_out;               // [100000, 2]
  float* eout = (float*)d_out + 200000;      // [3200000, 4]

  const int GE = (NE + 255)/256;
  const int GN = (NN + 255)/256;

  (void)hipMemsetAsync(cnt, 0, N*sizeof(int), stream);
  khist<<<GE, 256, 0, stream>>>(ei, cnt);
  kscanA<<<NB, 1024, 0, stream>>>(cnt, bsum);
  kscanB<<<1, 64, 0, stream>>>(bsum, boff, off + NN);
  kscanC<<<NB, 1024, 0, stream>>>(cnt, boff, off);
  k1<<<GN, 256, 0, stream>>>(x, c1Wx, c1as, c1ad, hs, hd);
  k2a<<<GE, 256, 0, stream>>>(ei, ea, c1We, c1ae, hs, hd, off, cnt, edata, epos);
  k34<<<(NN*16 + 255)/256, 256, 0, stream>>>(edata, off, x,
      c1b, c1Wx, c2Wx, c2as, c2ad, e1w1, hpk, hs, hd, uh, vh);
  k5m<<<GE, 256, 0, stream>>>(ei, ea, uh, vh, hs, hd,
      e1w1, e1b1, e1w2, e1b2, e1w3, e1b3, e1w4, e1b4,
      c2We, c2ae, elw1, elb1, elw2, elb2,
      epos, edata, eout);
  kagg2<<<(NN*64 + 255)/256, 256, 0, stream>>>(edata, off, (const u16*)hpk,
      c2b, nlw1, nlb1, nlw2, nlb2, nout);
}

// Round 23
// 693.689 us; speedup vs baseline: 1.1454x; 1.0111x over previous
//
#include <hip/hip_runtime.h>

#define NN 100000
#define NE 3200000
#define NB 98   // ceil(NN/1024)

typedef unsigned int u32;
typedef unsigned short u16;
typedef _Float16 f16x2 __attribute__((ext_vector_type(2)));
typedef _Float16 f16x8 __attribute__((ext_vector_type(8)));
typedef float fltx4 __attribute__((ext_vector_type(4)));
typedef __fp16 fp16v2 __attribute__((ext_vector_type(2)));

__device__ __forceinline__ int clampi(int s){
  s = s < 0 ? 0 : s;
  return s >= NN ? NN-1 : s;
}

__device__ __forceinline__ f16x2 pk2(float x, float y){
  fp16v2 r = __builtin_amdgcn_cvt_pkrtz(x, y);
  return __builtin_bit_cast(f16x2, r);
}
__device__ __forceinline__ u32 pk2u(float x, float y){
  return __builtin_bit_cast(u32, pk2(x, y));
}
__device__ __forceinline__ float dot2(f16x2 a, f16x2 b, float c){
  return __builtin_amdgcn_fdot2(a, b, c, false);
}
__device__ __forceinline__ float f16lo(u32 w){
  __fp16 h = __builtin_bit_cast(__fp16, (u16)(w & 0xffffu));
  return (float)h;
}
__device__ __forceinline__ float f16hi(u32 w){
  __fp16 h = __builtin_bit_cast(__fp16, (u16)(w >> 16));
  return (float)h;
}
__device__ __forceinline__ float f16u(u16 w){
  __fp16 h = __builtin_bit_cast(__fp16, w);
  return (float)h;
}

// ---------------- khist: cnt[d]++ ------------------------------------------
__global__ __launch_bounds__(256,8) void khist(const int* __restrict__ ei, int* __restrict__ cnt){
  int i = blockIdx.x*256 + threadIdx.x;
  if (i >= NE) return;
  atomicAdd(&cnt[clampi(ei[NE+i])], 1);
}

// ---------------- kscanA: per-block sums of cnt -----------------------------
__global__ __launch_bounds__(1024) void kscanA(const int* __restrict__ cnt, int* __restrict__ bsum){
  __shared__ int wsum[16];
  int tid = threadIdx.x;
  int i = blockIdx.x*1024 + tid;
  int x = (i < NN) ? cnt[i] : 0;
  #pragma unroll
  for (int ofs = 1; ofs < 64; ofs <<= 1) x += __shfl_xor(x, ofs, 64);
  if ((tid & 63) == 0) wsum[tid >> 6] = x;
  __syncthreads();
  if (tid == 0){
    int t = 0;
    #pragma unroll
    for (int k = 0; k < 16; k++) t += wsum[k];
    bsum[blockIdx.x] = t;
  }
}

// ---------------- kscanB: scan the 98 block sums ----------------------------
__global__ void kscanB(const int* __restrict__ bsum, int* __restrict__ boff, int* __restrict__ offN){
  if (threadIdx.x == 0){
    int c = 0;
    for (int b = 0; b < NB; b++){ boff[b] = c; c += bsum[b]; }
    offN[0] = c;
  }
}

// ---------------- kscanC: scan + offset; cnt=0; fused k1 (hs1/hd1) ----------
__global__ __launch_bounds__(1024) void kscanC(int* __restrict__ cnt, const int* __restrict__ boff,
                                               int* __restrict__ off,
                                               const float* __restrict__ x,
                                               const float* __restrict__ Wx,
                                               const float* __restrict__ asrc,
                                               const float* __restrict__ adst,
                                               float* __restrict__ hs1, float* __restrict__ hd1){
  __shared__ int wsum[16];
  __shared__ float wL[64], aS[16], aD[16];
  int tid = threadIdx.x;
  if (tid < 64) wL[tid] = Wx[tid];
  if (tid >= 64 && tid < 80) aS[tid-64] = asrc[tid-64];
  if (tid >= 80 && tid < 96) aD[tid-80] = adst[tid-80];
  int i = blockIdx.x*1024 + tid;
  int v = (i < NN) ? cnt[i] : 0;
  int xsc = v;
  #pragma unroll
  for (int ofs = 1; ofs < 64; ofs <<= 1){
    int t = __shfl_up(xsc, ofs, 64);
    if ((tid & 63) >= ofs) xsc += t;
  }
  if ((tid & 63) == 63) wsum[tid >> 6] = xsc;
  __syncthreads();
  if (tid < 16){
    int y = wsum[tid];
    #pragma unroll
    for (int ofs = 1; ofs < 16; ofs <<= 1){
      int t = __shfl_up(y, ofs, 64);
      if (tid >= ofs) y += t;
    }
    wsum[tid] = y;
  }
  __syncthreads();
  int wb = (tid >= 64) ? wsum[(tid >> 6) - 1] : 0;
  if (i < NN){
    off[i] = boff[blockIdx.x] + wb + xsc - v;
    cnt[i] = 0;
    float4 xr = ((const float4*)x)[i];
    float hs=0.f, hd=0.f;
    #pragma unroll
    for (int j=0;j<16;j++){
      float h = xr.x*wL[j*4+0] + xr.y*wL[j*4+1] + xr.z*wL[j*4+2] + xr.w*wL[j*4+3];
      hs += h*aS[j]; hd += h*aD[j];
    }
    hs1[i]=hs; hd1[i]=hd;
  }
}

// ---------------- k2a: alpha1 -> CSR scatter; records slot in epos ----------
__global__ __launch_bounds__(256,8) void k2a(const int* __restrict__ ei,
    const float* __restrict__ ea, const float* __restrict__ We, const float* __restrict__ aedge,
    const float* __restrict__ hs1, const float* __restrict__ hd1,
    const int* __restrict__ off, int* __restrict__ cnt, float2* __restrict__ edata,
    int* __restrict__ epos)
{
  __shared__ float w6[6];
  int tid = threadIdx.x;
  if (tid < 6){
    float acc = 0.f;
    for (int j=0;j<16;j++) acc += aedge[j] * We[j*6+tid];
    w6[tid] = acc;
  }
  __syncthreads();
  int i = blockIdx.x*256 + tid;
  if (i >= NE) return;
  int s = clampi(ei[i]);
  int d = clampi(ei[NE + i]);
  const float2* eap = (const float2*)ea + (size_t)i*3;
  float2 u0 = eap[0], u1 = eap[1], u2 = eap[2];
  float al = hs1[s] + hd1[d]
    + u0.x*w6[0] + u0.y*w6[1] + u1.x*w6[2]
    + u1.y*w6[3] + u2.x*w6[4] + u2.y*w6[5];
  al = al > 0.f ? al : 0.2f*al;
  float ex = __expf(al);
  int pos = off[d] + atomicAdd(&cnt[d], 1);
  edata[pos] = make_float2(ex, __int_as_float(s));
  epos[i] = pos;
}

// ---------------- k34: conv1 CSR reduce + node transform --------------------
__global__ __launch_bounds__(256,8) void k34(const float2* __restrict__ edata,
    const int* __restrict__ off, const float* __restrict__ x,
    const float* __restrict__ c1b, const float* __restrict__ Wx1, const float* __restrict__ Wx2,
    const float* __restrict__ a2s, const float* __restrict__ a2d,
    const float* __restrict__ w1p,
    u32* __restrict__ hpk, float* __restrict__ hs2, float* __restrict__ hd2,
    u32* __restrict__ uh, u32* __restrict__ vh)
{
  __shared__ float w0L[64], bL[16], wL[256], aS[16], aD[16];
  __shared__ float w1sL[32*16], w1dL[32*16];
  int tid = threadIdx.x;
  wL[tid] = Wx2[tid];
  if (tid < 64) w0L[tid] = Wx1[tid];
  if (tid < 16){ bL[tid]=c1b[tid]; aS[tid]=a2s[tid]; aD[tid]=a2d[tid]; }
  for (int idx=tid; idx<512; idx+=256){
    int j=idx>>4, k=idx&15;
    w1sL[idx] = w1p[j*38+k];
    w1dL[idx] = w1p[j*38+22+k];
  }
  __syncthreads();
  int t = blockIdx.x*256 + tid;
  int n = t >> 4;
  int j = t & 15;
  if (n >= NN) return;
  int f = j & 3, ks = j >> 2;
  int beg = off[n], end = off[n+1];
  float aj = 0.f, sl = 0.f;
  for (int k = beg + ks; k < end; k += 4){
    float2 p = edata[k];
    int src = __float_as_int(p.y);
    aj += p.x * x[(size_t)src*4 + f];
    sl += p.x;
  }
  aj += __shfl_xor(aj, 4, 64); aj += __shfl_xor(aj, 8, 64);
  sl += __shfl_xor(sl, 4, 64); sl += __shfl_xor(sl, 8, 64);
  float inv = 1.f/(sl + 1e-16f);
  float m0 = __shfl(aj, 0, 16)*inv;
  float m1 = __shfl(aj, 1, 16)*inv;
  float m2 = __shfl(aj, 2, 16)*inv;
  float m3 = __shfl(aj, 3, 16)*inv;
  float xvj = m0*w0L[j*4+0] + m1*w0L[j*4+1] + m2*w0L[j*4+2] + m3*w0L[j*4+3] + bL[j];
  float hv = 0.f, u0=0.f, u1=0.f, v0=0.f, v1=0.f;
  #pragma unroll
  for (int k=0;k<16;k++){
    float vk = __shfl(xvj, k, 16);
    hv += vk * wL[j*16+k];
    u0 += vk * w1sL[(2*j)*16+k];
    u1 += vk * w1sL[(2*j+1)*16+k];
    v0 += vk * w1dL[(2*j)*16+k];
    v1 += vk * w1dL[(2*j+1)*16+k];
  }
  ((u16*)hpk)[(size_t)n*16 + j] = (u16)(pk2u(hv, 0.f) & 0xffffu);
  uh[(size_t)n*16 + j] = pk2u(u0, u1);
  vh[(size_t)n*16 + j] = pk2u(v0, v1);
  float hsp = hv*aS[j], hdp = hv*aD[j];
  #pragma unroll
  for (int ofs=1; ofs<16; ofs<<=1){
    hsp += __shfl_xor(hsp, ofs, 64);
    hdp += __shfl_xor(hdp, ofs, 64);
  }
  if (j == 0){ hs2[n]=hsp; hd2[n]=hdp; }
}

// ---------------- k5m: edge MLP with MFMA L2/L3 + folded head + scatter -----
// r22 config (257us) + LDS diet: B-frag staging aliased into a2L (B-frags are
// consumed into registers before the pre-loop barrier; a2L is first written
// after the first in-loop barrier). LDS 40448 -> 32256 B => 5 blocks/CU.
#define A13S 20
#define A2S  36
__global__ __launch_bounds__(256,4) void k5m(
    const int* __restrict__ ei, const float* __restrict__ ea,
    const u32* __restrict__ uh, const u32* __restrict__ vh,
    const float* __restrict__ hs2, const float* __restrict__ hd2,
    const float* w1p, const float* b1p, const float* w2p, const float* b2p,
    const float* w3p, const float* b3p, const float* w4p, const float* b4p,
    const float* We2, const float* a2e,
    const float* ew1p, const float* eb1p, const float* ew2p, const float* eb2p,
    const int* __restrict__ epos, float2* __restrict__ edata,
    float* __restrict__ eout)
{
  __shared__ __align__(16) u32 a13L[4][64*A13S];   // per-wave 5120B: a1, later a3
  __shared__ __align__(16) u32 a2L[4][16*A2S];     // per-wave 2304B: a2 row-tile
                                                   // (also B-frag scratch at init)
  __shared__ __align__(16) f16x2 w1eh[32*4];  __shared__ float b1L[32];
  __shared__ float b2L[64], b3L[32];
  __shared__ __align__(16) f16x2 M1h[16*16];  __shared__ float c1L[16];
  __shared__ __align__(16) f16x2 ew2h[4*8];   __shared__ float eb2L[4];
  __shared__ __align__(16) f16x2 w16w4h[16];
  __shared__ float w16L[16];  __shared__ float w16b4L;

  uint4* bsc = (uint4*)&a2L[0][0];   // 512 x 16B = 8192B <= 9216B of a2L
  int tid = threadIdx.x;
  // ---- init phase A ----
  if (tid < 128){
    int j=tid>>2, kk=tid&3;
    int k0=2*kk, k1=2*kk+1;
    float v0 = (k0<6) ? w1p[j*38+16+k0] : 0.f;
    float v1 = (k1<6) ? w1p[j*38+16+k1] : 0.f;
    w1eh[tid] = pk2(v0, v1);
  }
  {
    // L2 B-frags at bsc[c*64+l]
    int c = tid>>6, l = tid&63;
    int j = c*16 + (l&15), kb = (l>>4)*8;
    const float* src = w2p + j*32 + kb;
    uint4 q;
    q.x = pk2u(src[0], src[1]); q.y = pk2u(src[2], src[3]);
    q.z = pk2u(src[4], src[5]); q.w = pk2u(src[6], src[7]);
    bsc[c*64 + l] = q;
  }
  {
    // L3 B-frags at bsc[256 + (kt*2+c)*64 + l]
    int kt = tid>>7, c = (tid>>6)&1, l = tid&63;
    int j = c*16 + (l&15), kb = kt*32 + (l>>4)*8;
    const float* src = w3p + j*64 + kb;
    uint4 q;
    q.x = pk2u(src[0], src[1]); q.y = pk2u(src[2], src[3]);
    q.z = pk2u(src[4], src[5]); q.w = pk2u(src[6], src[7]);
    bsc[256 + (kt*2+c)*64 + l] = q;
  }
  if (tid < 64) b2L[tid] = b2p[tid];
  if (tid < 32){ b1L[tid] = b1p[tid]; b3L[tid] = b3p[tid]; }
  {
    int o = tid>>4, p = tid&15;
    float m0=0.f, m1=0.f;
    #pragma unroll
    for (int q=0;q<16;q++){
      float w = ew1p[o*16+q];
      m0 += w * w4p[q*32 + 2*p];
      m1 += w * w4p[q*32 + 2*p + 1];
    }
    M1h[o*16+p] = pk2(m0, m1);
  }
  if (tid < 16){
    float acc = eb1p[tid];
    for (int q=0;q<16;q++) acc += ew1p[tid*16+q]*b4p[q];
    c1L[tid] = acc;
    float w=0.f;
    for (int j=0;j<16;j++) w += a2e[j] * We2[j*16+tid];
    w16L[tid] = w;
  }
  if (tid < 32){
    int j=tid>>3, kk=tid&7;
    ew2h[tid] = pk2(ew2p[j*16+2*kk], ew2p[j*16+2*kk+1]);
  }
  if (tid < 4) eb2L[tid] = eb2p[tid];
  __syncthreads();
  // ---- init phase B (needs w16L) ----
  if (tid < 16){
    float s0=0.f, s1=0.f;
    for (int q=0;q<16;q++){
      s0 += w16L[q]*w4p[q*32 + 2*tid];
      s1 += w16L[q]*w4p[q*32 + 2*tid + 1];
    }
    w16w4h[tid] = pk2(s0, s1);
  }
  if (tid == 0){
    float acc=0.f;
    for (int q=0;q<16;q++) acc += w16L[q]*b4p[q];
    w16b4L = acc;
  }
  __syncthreads();

  int wid = tid>>6, lane = tid&63;
  int cl = lane & 15, g = lane >> 4;
  u32* a13 = a13L[wid];
  u32* a2u = a2L[wid];
  int i = blockIdx.x*256 + tid;   // always < NE (grid exact)
  int s = clampi(ei[i]);
  int d = clampi(ei[NE + i]);

  // ---- layer 1 (per-lane, f16 dot2) ----
  u32 a1h[16];
  {
    const float2* eap = (const float2*)ea + (size_t)i*3;
    float2 e0=eap[0], e1=eap[1], e2=eap[2];
    f16x2 eh[4];
    eh[0]=pk2(e0.x,e0.y); eh[1]=pk2(e1.x,e1.y); eh[2]=pk2(e2.x,e2.y); eh[3]=pk2(0.f,0.f);
    const uint4* up = (const uint4*)(uh + (size_t)s*16);
    const uint4* vp = (const uint4*)(vh + (size_t)d*16);
    uint4 U[4], V[4];
    #pragma unroll
    for (int q=0;q<4;q++){ U[q]=up[q]; V[q]=vp[q]; }
    u32 uw[16], vw[16];
    #pragma unroll
    for (int q=0;q<4;q++){
      uw[4*q]=U[q].x; uw[4*q+1]=U[q].y; uw[4*q+2]=U[q].z; uw[4*q+3]=U[q].w;
      vw[4*q]=V[q].x; vw[4*q+1]=V[q].y; vw[4*q+2]=V[q].z; vw[4*q+3]=V[q].w;
    }
    #pragma unroll
    for (int j=0;j<16;j++){
      float t0 = b1L[2*j]   + f16lo(uw[j]) + f16lo(vw[j]);
      float t1 = b1L[2*j+1] + f16hi(uw[j]) + f16hi(vw[j]);
      #pragma unroll
      for (int kk=0;kk<4;kk++){
        t0 = dot2(eh[kk], w1eh[(2*j)*4+kk],   t0);
        t1 = dot2(eh[kk], w1eh[(2*j+1)*4+kk], t1);
      }
      a1h[j] = pk2u(fmaxf(t0,0.f), fmaxf(t1,0.f));
    }
  }
  // stage a1: row = lane, padded stride
  {
    uint4* dst = (uint4*)(a13 + lane*A13S);
    dst[0] = make_uint4(a1h[0],a1h[1],a1h[2],a1h[3]);
    dst[1] = make_uint4(a1h[4],a1h[5],a1h[6],a1h[7]);
    dst[2] = make_uint4(a1h[8],a1h[9],a1h[10],a1h[11]);
    dst[3] = make_uint4(a1h[12],a1h[13],a1h[14],a1h[15]);
  }
  // load B fragments to regs from the shared scratch (before any a2 write)
  f16x8 fb2[4], fb3[4];
  #pragma unroll
  for (int c=0;c<4;c++) fb2[c] = __builtin_bit_cast(f16x8, bsc[c*64 + lane]);
  #pragma unroll
  for (int q=0;q<4;q++) fb3[q] = __builtin_bit_cast(f16x8, bsc[256 + q*64 + lane]);
  __syncthreads();

  // ---- L2 + L3 per row-tile ----
  #pragma unroll
  for (int r=0;r<4;r++){
    __syncthreads();                 // a2 WAR from previous r (and B-frag reads)
    uint4 av = *(const uint4*)(a13 + (r*16 + cl)*A13S + g*4);
    f16x8 af = __builtin_bit_cast(f16x8, av);
    _Float16* a2h_ = (_Float16*)a2u;
    #pragma unroll
    for (int c=0;c<4;c++){
      float b = b2L[c*16 + cl];
      fltx4 acc = {b,b,b,b};
      acc = __builtin_amdgcn_mfma_f32_16x16x32_f16(af, fb2[c], acc, 0, 0, 0);
      int col = c*16 + cl;
      int rowb = g*4;
      a2h_[(rowb+0)*(2*A2S) + col] = (_Float16)fmaxf(acc[0], 0.f);
      a2h_[(rowb+1)*(2*A2S) + col] = (_Float16)fmaxf(acc[1], 0.f);
      a2h_[(rowb+2)*(2*A2S) + col] = (_Float16)fmaxf(acc[2], 0.f);
      a2h_[(rowb+3)*(2*A2S) + col] = (_Float16)fmaxf(acc[3], 0.f);
    }
    __syncthreads();                 // a2 ready
    uint4 a20 = *(const uint4*)(a2u + cl*A2S + g*4);
    uint4 a21 = *(const uint4*)(a2u + cl*A2S + 16 + g*4);
    f16x8 af0 = __builtin_bit_cast(f16x8, a20);
    f16x8 af1 = __builtin_bit_cast(f16x8, a21);
    _Float16* a3w = (_Float16*)a13;
    #pragma unroll
    for (int c=0;c<2;c++){
      float b = b3L[c*16 + cl];
      fltx4 acc = {b,b,b,b};
      acc = __builtin_amdgcn_mfma_f32_16x16x32_f16(af0, fb3[0*2+c], acc, 0, 0, 0);
      acc = __builtin_amdgcn_mfma_f32_16x16x32_f16(af1, fb3[1*2+c], acc, 0, 0, 0);
      int col = c*16 + cl;
      int row = r*16 + g*4;
      a3w[(row+0)*(2*A13S) + col] = (_Float16)fmaxf(acc[0], 0.f);
      a3w[(row+1)*(2*A13S) + col] = (_Float16)fmaxf(acc[1], 0.f);
      a3w[(row+2)*(2*A13S) + col] = (_Float16)fmaxf(acc[2], 0.f);
      a3w[(row+3)*(2*A13S) + col] = (_Float16)fmaxf(acc[3], 0.f);
    }
  }
  __syncthreads();                   // a3 complete
  // readback a3 of own edge
  u32 a3h[16];
  {
    const uint4* srcp = (const uint4*)(a13 + lane*A13S);
    uint4 q0=srcp[0], q1=srcp[1], q2=srcp[2], q3=srcp[3];
    a3h[0]=q0.x; a3h[1]=q0.y; a3h[2]=q0.z; a3h[3]=q0.w;
    a3h[4]=q1.x; a3h[5]=q1.y; a3h[6]=q1.z; a3h[7]=q1.w;
    a3h[8]=q2.x; a3h[9]=q2.y; a3h[10]=q2.z; a3h[11]=q2.w;
    a3h[12]=q3.x; a3h[13]=q3.y; a3h[14]=q3.z; a3h[15]=q3.w;
  }
  // ---- folded L4 + head1: t = relu(M1.a3 + c1) ----
  f16x2 th[8];
  #pragma unroll
  for (int o=0;o<8;o++){
    float t0 = c1L[2*o], t1 = c1L[2*o+1];
    #pragma unroll
    for (int kp=0;kp<16;kp++){
      f16x2 a = __builtin_bit_cast(f16x2, a3h[kp]);
      t0 = dot2(a, M1h[(2*o)*16+kp],   t0);
      t1 = dot2(a, M1h[(2*o+1)*16+kp], t1);
    }
    th[o] = pk2(fmaxf(t0,0.f), fmaxf(t1,0.f));
  }
  // ---- head2 + log_softmax(4) ----
  float y0 = eb2L[0], y1 = eb2L[1], y2 = eb2L[2], y3 = eb2L[3];
  #pragma unroll
  for (int kk=0;kk<8;kk++){
    y0 = dot2(th[kk], ew2h[0*8+kk], y0);
    y1 = dot2(th[kk], ew2h[1*8+kk], y1);
    y2 = dot2(th[kk], ew2h[2*8+kk], y2);
    y3 = dot2(th[kk], ew2h[3*8+kk], y3);
  }
  y0 = fmaxf(y0,0.f); y1 = fmaxf(y1,0.f); y2 = fmaxf(y2,0.f); y3 = fmaxf(y3,0.f);
  float m = fmaxf(fmaxf(y0,y1), fmaxf(y2,y3));
  float l = m + __logf(__expf(y0-m)+__expf(y1-m)+__expf(y2-m)+__expf(y3-m));
  float4 eo; eo.x = y0-l; eo.y = y1-l; eo.z = y2-l; eo.w = y3-l;
  ((float4*)eout)[i] = eo;

  // ---- conv2 alpha via folded w16w4; scatter to precomputed slot ----
  float al = hs2[s] + hd2[d] + w16b4L;
  #pragma unroll
  for (int kp=0;kp<16;kp++){
    f16x2 a = __builtin_bit_cast(f16x2, a3h[kp]);
    al = dot2(a, w16w4h[kp], al);
  }
  al = al > 0.f ? al : 0.2f*al;
  float ex = __expf(al);
  edata[epos[i]] = make_float2(ex, __int_as_float(s));
}

// ---------------- kagg2: conv2 CSR reduce + fused node head ----------------
__global__ __launch_bounds__(256,8) void kagg2(const float2* __restrict__ edata,
    const int* __restrict__ off, const u16* __restrict__ hpk,
    const float* __restrict__ c2b,
    const float* __restrict__ w1p, const float* __restrict__ b1p,
    const float* __restrict__ w2p, const float* __restrict__ b2p,
    float* __restrict__ nout)
{
  __shared__ float w1L[256], cb[16], b1L[16], w2L[32], b2L[2];
  int tid = threadIdx.x;
  w1L[tid] = w1p[tid];
  if (tid < 16){ cb[tid] = c2b[tid]; b1L[tid] = b1p[tid]; }
  if (tid < 32) w2L[tid] = w2p[tid];
  if (tid < 2)  b2L[tid] = b2p[tid];
  __syncthreads();
  int t = blockIdx.x*256 + tid;
  int n = t >> 6;
  int l = t & 63;
  if (n >= NN) return;
  int j = l & 15, ks = l >> 4;
  int beg = off[n], end = off[n+1];
  float aj = 0.f, sl = 0.f;
  for (int k = beg + ks; k < end; k += 4){
    float2 p = edata[k];
    int src = __float_as_int(p.y);
    aj += p.x * f16u(hpk[(size_t)src*16 + j]);
    sl += p.x;
  }
  aj += __shfl_xor(aj, 16, 64); aj += __shfl_xor(aj, 32, 64);
  sl += __shfl_xor(sl, 16, 64); sl += __shfl_xor(sl, 32, 64);
  float inv = 1.f/(sl + 1e-16f);
  float vj = aj*inv + cb[j];
  float tj = b1L[j];
  #pragma unroll
  for (int k=0;k<16;k++){
    float vk = __shfl(vj, k, 16);
    tj += vk * w1L[j*16 + k];
  }
  tj = fmaxf(tj, 0.f);
  float p0 = tj * w2L[j];
  float p1 = tj * w2L[16 + j];
  #pragma unroll
  for (int ofs=1; ofs<16; ofs<<=1){
    p0 += __shfl_xor(p0, ofs, 64);
    p1 += __shfl_xor(p1, ofs, 64);
  }
  if (l == 0){
    float y0 = fmaxf(p0 + b2L[0], 0.f);
    float y1 = fmaxf(p1 + b2L[1], 0.f);
    float m = fmaxf(y0, y1);
    float lg = m + __logf(__expf(y0-m) + __expf(y1-m));
    float2 no; no.x = y0-lg; no.y = y1-lg;
    ((float2*)nout)[n] = no;
  }
}

extern "C" void kernel_launch(void* const* d_in, const int* in_sizes, int n_in,
                              void* d_out, int out_size, void* d_ws, size_t ws_size,
                              hipStream_t stream)
{
  const float* x  = (const float*)d_in[0];
  const int* ei   = (const int*)d_in[1];
  const float* ea = (const float*)d_in[2];
  const float* c1Wx = (const float*)d_in[3];
  const float* c1We = (const float*)d_in[4];
  const float* c1as = (const float*)d_in[5];
  const float* c1ad = (const float*)d_in[6];
  const float* c1ae = (const float*)d_in[7];
  const float* c1b  = (const float*)d_in[8];
  const float* e1w1 = (const float*)d_in[9];
  const float* e1b1 = (const float*)d_in[10];
  const float* e1w2 = (const float*)d_in[11];
  const float* e1b2 = (const float*)d_in[12];
  const float* e1w3 = (const float*)d_in[13];
  const float* e1b3 = (const float*)d_in[14];
  const float* e1w4 = (const float*)d_in[15];
  const float* e1b4 = (const float*)d_in[16];
  const float* c2Wx = (const float*)d_in[17];
  const float* c2We = (const float*)d_in[18];
  const float* c2as = (const float*)d_in[19];
  const float* c2ad = (const float*)d_in[20];
  const float* c2ae = (const float*)d_in[21];
  const float* c2b  = (const float*)d_in[22];
  const float* nlw1 = (const float*)d_in[23];
  const float* nlb1 = (const float*)d_in[24];
  const float* nlw2 = (const float*)d_in[25];
  const float* nlb2 = (const float*)d_in[26];
  const float* elw1 = (const float*)d_in[27];
  const float* elb1 = (const float*)d_in[28];
  const float* elw2 = (const float*)d_in[29];
  const float* elb2 = (const float*)d_in[30];

  float* ws = (float*)d_ws;
  const size_t N = NN;
  int* off   = (int*)ws;                     // N+8
  int* cnt   = (int*)ws + (N + 8);           // N
  int* bsum  = (int*)ws + (2*N + 8);         // 128
  int* boff  = (int*)ws + (2*N + 136);       // 128
  u32* hpk   = (u32*)(ws + 2*N + 264);       // 8N u32 (f16x2-packed h2)
  float* hs  = ws + 10*N + 264;              // N
  float* hd  = hs + N;                       // N
  u32* uh    = (u32*)(hd + N);               // 16N u32
  u32* vh    = uh + 16*N;                    // 16N u32
  float2* edata = (float2*)(vh + 16*N);      // NE float2
  int* epos  = (int*)(edata + NE);           // NE int

  float* nout = (float*)d_out;               // [100000, 2]
  float* eout = (float*)d_out + 200000;      // [3200000, 4]

  const int GE = (NE + 255)/256;

  (void)hipMemsetAsync(cnt, 0, N*sizeof(int), stream);
  khist<<<GE, 256, 0, stream>>>(ei, cnt);
  kscanA<<<NB, 1024, 0, stream>>>(cnt, bsum);
  kscanB<<<1, 64, 0, stream>>>(bsum, boff, off + NN);
  kscanC<<<NB, 1024, 0, stream>>>(cnt, boff, off, x, c1Wx, c1as, c1ad, hs, hd);
  k2a<<<GE, 256, 0, stream>>>(ei, ea, c1We, c1ae, hs, hd, off, cnt, edata, epos);
  k34<<<(NN*16 + 255)/256, 256, 0, stream>>>(edata, off, x,
      c1b, c1Wx, c2Wx, c2as, c2ad, e1w1, hpk, hs, hd, uh, vh);
  k5m<<<GE, 256, 0, stream>>>(ei, ea, uh, vh, hs, hd,
      e1w1, e1b1, e1w2, e1b2, e1w3, e1b3, e1w4, e1b4,
      c2We, c2ae, elw1, elb1, elw2, elb2,
      epos, edata, eout);
  kagg2<<<(NN*64 + 255)/256, 256, 0, stream>>>(edata, off, (const u16*)hpk,
      c2b, nlw1, nlb1, nlw2, nlb2, nout);
}